// Round 1
// baseline (643.558 us; speedup 1.0000x reference)
//
#include <hip/hip_runtime.h>
#include <math.h>

#define CCAP 640

__device__ __forceinline__ float waveReduceSum(float v) {
    #pragma unroll
    for (int off = 32; off >= 1; off >>= 1) v += __shfl_down(v, off, 64);
    return v;
}

// ---------------------------------------------------------------------------
// Kernel 1: gating. One block per patch (n = b*256 + pr*16 + pc).
// Computes 3 image-channel sums + 20 positional-channel sums over the 16x16
// patch, then logits -> softmax -> argmax. Writes e_idx[n], ptop[n], and
// atomically accumulates per-expert prob sums (for aux loss).
// ---------------------------------------------------------------------------
__global__ __launch_bounds__(256) void k_gate(const float* __restrict__ X,
        const float* __restrict__ gw, const float* __restrict__ gb,
        float* __restrict__ psum, int* __restrict__ eidx,
        float* __restrict__ ptop)
{
    int n = blockIdx.x;
    int b = n >> 8, p = n & 255, pr = p >> 4, pc = p & 15;
    int tid = threadIdx.x;
    int i = tid >> 4, j = tid & 15;

    float vals[23];
    float gx  = (float)(pc * 16 + j) * (1.0f / 256.0f);
    float gy  = (float)(pr * 16 + i) * (1.0f / 256.0f);
    float pcx = ((float)pc + 0.5f) * (1.0f / 16.0f);
    float pcy = ((float)pr + 0.5f) * (1.0f / 16.0f);

    #pragma unroll
    for (int c = 0; c < 3; ++c)
        vals[c] = X[((size_t)(b * 3 + c) * 256 + pr * 16 + i) * 256 + pc * 16 + j];
    vals[3] = gx; vals[4] = gy; vals[5] = pcx; vals[6] = pcy;

    float tarr[4] = {gx, gy, pcx, pcy};
    int idx = 7;
    #pragma unroll
    for (int f = 0; f < 2; ++f) {
        float s = (f == 0 ? 1.0f : 2.0f) * 2.0f * 3.14159265358979323846f;
        #pragma unroll
        for (int t = 0; t < 4; ++t) {
            vals[idx++] = sinf(s * tarr[t]);
            vals[idx++] = cosf(s * tarr[t]);
        }
    }

    __shared__ float red[4][23];
    __shared__ float sums[23];
    int wave = tid >> 6, lane = tid & 63;
    #pragma unroll
    for (int k = 0; k < 23; ++k) {
        float v = waveReduceSum(vals[k]);
        if (lane == 0) red[wave][k] = v;
    }
    __syncthreads();
    if (tid < 23) sums[tid] = red[0][tid] + red[1][tid] + red[2][tid] + red[3][tid];
    __syncthreads();

    if (tid == 0) {
        float lg[8];
        float mx = -1e30f;
        #pragma unroll
        for (int e = 0; e < 8; ++e) {
            float acc = 0.f;
            #pragma unroll
            for (int c = 0; c < 23; ++c) acc += sums[c] * gw[e * 23 + c];
            lg[e] = acc * (1.0f / 256.0f) + gb[e];
            mx = fmaxf(mx, lg[e]);
        }
        float den = 0.f;
        float pe[8];
        #pragma unroll
        for (int e = 0; e < 8; ++e) { pe[e] = expf(lg[e] - mx); den += pe[e]; }
        float invden = 1.0f / den;
        int am = 0; float best = lg[0];
        #pragma unroll
        for (int e = 1; e < 8; ++e) if (lg[e] > best) { best = lg[e]; am = e; }
        eidx[n] = am;
        ptop[n] = pe[am] * invden;
        #pragma unroll
        for (int e = 0; e < 8; ++e) atomicAdd(&psum[e], pe[e] * invden);
    }
}

// ---------------------------------------------------------------------------
// Kernel 2: ordered per-expert rank (cumsum semantics), capacity mask, gates,
// and aux loss. Single block of 256 threads; each thread owns 16 consecutive n.
// ---------------------------------------------------------------------------
__global__ __launch_bounds__(256) void k_rank(const int* __restrict__ eidx,
        const float* __restrict__ ptop, const float* __restrict__ psum,
        float* __restrict__ gates, float* __restrict__ out_aux)
{
    __shared__ int hist[256][8];
    __shared__ int totals[8];
    int t = threadIdx.x;

    int h[8] = {0, 0, 0, 0, 0, 0, 0, 0};
    int myE[16];
    #pragma unroll
    for (int k = 0; k < 16; ++k) {
        int e = eidx[t * 16 + k];
        myE[k] = e;
        h[e]++;
    }
    #pragma unroll
    for (int e = 0; e < 8; ++e) hist[t][e] = h[e];
    __syncthreads();

    if (t < 8) {
        int running = 0;
        for (int q = 0; q < 256; ++q) {
            int c = hist[q][t];
            hist[q][t] = running;   // exclusive prefix, in place
            running += c;
        }
        totals[t] = running;
    }
    __syncthreads();

    int run[8];
    #pragma unroll
    for (int e = 0; e < 8; ++e) run[e] = hist[t][e];
    #pragma unroll
    for (int k = 0; k < 16; ++k) {
        int n = t * 16 + k;
        int e = myE[k];
        int r = run[e]++;
        gates[n] = (r < CCAP) ? ptop[n] : 0.0f;
    }

    if (t == 0) {
        float aux = 0.f;
        #pragma unroll
        for (int e = 0; e < 8; ++e) {
            float fe = (float)min(totals[e], CCAP) * (1.0f / 4096.0f);
            float pe = psum[e] * (1.0f / 4096.0f);
            aux += fe * pe;
        }
        out_aux[0] = 8.0f * aux;
    }
}

// ---------------------------------------------------------------------------
// Kernel 3: per-patch 3x3 SAME conv (3->8 ch, zero-padded per patch), bias,
// ReLU, per-output-channel pixel sum, times gate. One block per patch.
// ---------------------------------------------------------------------------
__global__ __launch_bounds__(256) void k_conv(const float* __restrict__ X,
        const float* __restrict__ ew, const float* __restrict__ eb,
        const int* __restrict__ eidx, const float* __restrict__ gates,
        float* __restrict__ znc)
{
    int n = blockIdx.x;
    int b = n >> 8, p = n & 255, pr = p >> 4, pc = p & 15;
    int tid = threadIdx.x;
    int i = tid >> 4, j = tid & 15;

    __shared__ float s[3][18][18];
    __shared__ float wsm[216];
    __shared__ float bsm[8];
    __shared__ int esh;
    __shared__ float gsh;

    if (tid == 0) { esh = eidx[n]; gsh = gates[n]; }
    float* sf = &s[0][0][0];
    for (int idx = tid; idx < 3 * 18 * 18; idx += 256) sf[idx] = 0.f;
    __syncthreads();

    int e = esh;
    for (int idx = tid; idx < 216; idx += 256) wsm[idx] = ew[e * 216 + idx];
    if (tid < 8) bsm[tid] = eb[e * 8 + tid];
    #pragma unroll
    for (int c = 0; c < 3; ++c)
        s[c][i + 1][j + 1] =
            X[((size_t)(b * 3 + c) * 256 + pr * 16 + i) * 256 + pc * 16 + j];
    __syncthreads();

    float y[8];
    #pragma unroll
    for (int co = 0; co < 8; ++co) {
        float acc = bsm[co];
        #pragma unroll
        for (int ci = 0; ci < 3; ++ci)
            #pragma unroll
            for (int di = 0; di < 3; ++di)
                #pragma unroll
                for (int dj = 0; dj < 3; ++dj)
                    acc += s[ci][i + di][j + dj] * wsm[co * 27 + ci * 9 + di * 3 + dj];
        y[co] = fmaxf(acc, 0.f);
    }

    __shared__ float red[4][8];
    int wave = tid >> 6, lane = tid & 63;
    #pragma unroll
    for (int co = 0; co < 8; ++co) {
        float v = waveReduceSum(y[co]);
        if (lane == 0) red[wave][co] = v;
    }
    __syncthreads();
    if (tid < 8)
        znc[(size_t)n * 8 + tid] =
            gsh * (red[0][tid] + red[1][tid] + red[2][tid] + red[3][tid]);
}

// ---------------------------------------------------------------------------
// Kernel 4: feat[b][512] from znc (2x2 patch pool / 1024), then
// logits_cls[b] = feat @ lin_w + lin_b. One block per batch image.
// ---------------------------------------------------------------------------
__global__ __launch_bounds__(256) void k_cls(const float* __restrict__ znc,
        const float* __restrict__ lw, const float* __restrict__ lb,
        float* __restrict__ out)
{
    int b = blockIdx.x;
    int tid = threadIdx.x;
    __shared__ float feat[512];

    for (int f = tid; f < 512; f += 256) {
        int co = f >> 6, rem = f & 63, py = rem >> 3, px = rem & 7;
        float sum = 0.f;
        #pragma unroll
        for (int dy = 0; dy < 2; ++dy)
            #pragma unroll
            for (int dx = 0; dx < 2; ++dx) {
                int n = b * 256 + (2 * py + dy) * 16 + (2 * px + dx);
                sum += znc[(size_t)n * 8 + co];
            }
        feat[f] = sum * (1.0f / 1024.0f);
    }
    __syncthreads();

    for (int k = tid; k < 1000; k += 256) {
        float acc = lb[k];
        #pragma unroll 8
        for (int f = 0; f < 512; ++f) acc += feat[f] * lw[(size_t)f * 1000 + k];
        out[b * 1000 + k] = acc;
    }
}

extern "C" void kernel_launch(void* const* d_in, const int* in_sizes, int n_in,
                              void* d_out, int out_size, void* d_ws, size_t ws_size,
                              hipStream_t stream) {
    const float* X  = (const float*)d_in[0];
    const float* ew = (const float*)d_in[1];
    const float* eb = (const float*)d_in[2];
    const float* gw = (const float*)d_in[3];
    const float* gb = (const float*)d_in[4];
    const float* lw = (const float*)d_in[5];
    const float* lb = (const float*)d_in[6];
    float* out = (float*)d_out;

    char* ws = (char*)d_ws;
    float* psum  = (float*)(ws + 0);                  // 8 floats
    int*   eidx  = (int*)  (ws + 64);                 // 4096 ints
    float* ptop  = (float*)(ws + 64 + 4096 * 4);      // 4096 floats
    float* gates = (float*)(ws + 64 + 4096 * 8);      // 4096 floats
    float* znc   = (float*)(ws + 64 + 4096 * 12);     // 4096*8 floats

    hipMemsetAsync(psum, 0, 8 * sizeof(float), stream);
    k_gate<<<4096, 256, 0, stream>>>(X, gw, gb, psum, eidx, ptop);
    k_rank<<<1, 256, 0, stream>>>(eidx, ptop, psum, gates, out + 16000);
    k_conv<<<4096, 256, 0, stream>>>(X, ew, eb, eidx, gates, znc);
    k_cls<<<16, 256, 0, stream>>>(znc, lw, lb, out);
}

// Round 2
// 178.468 us; speedup vs baseline: 3.6060x; 3.6060x over previous
//
#include <hip/hip_runtime.h>
#include <math.h>

#define CCAP 640

__device__ __forceinline__ float waveReduceSum(float v) {
    #pragma unroll
    for (int off = 32; off >= 1; off >>= 1) v += __shfl_down(v, off, 64);
    return v;
}

// ---------------------------------------------------------------------------
// Kernel 1: gating. One block per patch (n = b*256 + pr*16 + pc).
// Computes 3 image-channel sums + 20 positional-channel sums over the 16x16
// patch, then logits -> softmax -> argmax. Writes e_idx[n] and the full
// probability row probs[n][8] (NO global atomics -- reduced in k_rank).
// ---------------------------------------------------------------------------
__global__ __launch_bounds__(256) void k_gate(const float* __restrict__ X,
        const float* __restrict__ gw, const float* __restrict__ gb,
        int* __restrict__ eidx, float* __restrict__ probs)
{
    int n = blockIdx.x;
    int b = n >> 8, p = n & 255, pr = p >> 4, pc = p & 15;
    int tid = threadIdx.x;
    int i = tid >> 4, j = tid & 15;

    float vals[23];
    float gx  = (float)(pc * 16 + j) * (1.0f / 256.0f);
    float gy  = (float)(pr * 16 + i) * (1.0f / 256.0f);
    float pcx = ((float)pc + 0.5f) * (1.0f / 16.0f);
    float pcy = ((float)pr + 0.5f) * (1.0f / 16.0f);

    #pragma unroll
    for (int c = 0; c < 3; ++c)
        vals[c] = X[((size_t)(b * 3 + c) * 256 + pr * 16 + i) * 256 + pc * 16 + j];
    vals[3] = gx; vals[4] = gy; vals[5] = pcx; vals[6] = pcy;

    float tarr[4] = {gx, gy, pcx, pcy};
    int idx = 7;
    #pragma unroll
    for (int f = 0; f < 2; ++f) {
        float s = (f == 0 ? 1.0f : 2.0f) * 2.0f * 3.14159265358979323846f;
        #pragma unroll
        for (int t = 0; t < 4; ++t) {
            vals[idx++] = sinf(s * tarr[t]);
            vals[idx++] = cosf(s * tarr[t]);
        }
    }

    __shared__ float red[4][23];
    __shared__ float sums[23];
    int wave = tid >> 6, lane = tid & 63;
    #pragma unroll
    for (int k = 0; k < 23; ++k) {
        float v = waveReduceSum(vals[k]);
        if (lane == 0) red[wave][k] = v;
    }
    __syncthreads();
    if (tid < 23) sums[tid] = red[0][tid] + red[1][tid] + red[2][tid] + red[3][tid];
    __syncthreads();

    if (tid == 0) {
        float lg[8];
        float mx = -1e30f;
        #pragma unroll
        for (int e = 0; e < 8; ++e) {
            float acc = 0.f;
            #pragma unroll
            for (int c = 0; c < 23; ++c) acc += sums[c] * gw[e * 23 + c];
            lg[e] = acc * (1.0f / 256.0f) + gb[e];
            mx = fmaxf(mx, lg[e]);
        }
        float den = 0.f;
        float pe[8];
        #pragma unroll
        for (int e = 0; e < 8; ++e) { pe[e] = expf(lg[e] - mx); den += pe[e]; }
        float invden = 1.0f / den;
        int am = 0; float best = lg[0];
        #pragma unroll
        for (int e = 1; e < 8; ++e) if (lg[e] > best) { best = lg[e]; am = e; }
        eidx[n] = am;
        #pragma unroll
        for (int e = 0; e < 8; ++e) probs[(size_t)n * 8 + e] = pe[e] * invden;
    }
}

// ---------------------------------------------------------------------------
// Kernel 2: ordered per-expert rank (cumsum semantics), capacity mask, gates,
// prob-sum reduction, and aux loss. Single block of 256 threads; each thread
// owns 16 consecutive n.
// ---------------------------------------------------------------------------
__global__ __launch_bounds__(256) void k_rank(const int* __restrict__ eidx,
        const float* __restrict__ probs, float* __restrict__ gates,
        float* __restrict__ out_aux)
{
    __shared__ int hist[256][8];
    __shared__ int totals[8];
    __shared__ float pred[4][8];
    __shared__ float psum[8];
    int t = threadIdx.x;
    int wave = t >> 6, lane = t & 63;

    int h[8] = {0, 0, 0, 0, 0, 0, 0, 0};
    float lp[8] = {0.f, 0.f, 0.f, 0.f, 0.f, 0.f, 0.f, 0.f};
    int myE[16];
    #pragma unroll
    for (int k = 0; k < 16; ++k) {
        int n = t * 16 + k;
        int e = eidx[n];
        myE[k] = e;
        h[e]++;
        #pragma unroll
        for (int q = 0; q < 8; ++q) lp[q] += probs[(size_t)n * 8 + q];
    }
    #pragma unroll
    for (int e = 0; e < 8; ++e) hist[t][e] = h[e];
    #pragma unroll
    for (int e = 0; e < 8; ++e) {
        float v = waveReduceSum(lp[e]);
        if (lane == 0) pred[wave][e] = v;
    }
    __syncthreads();

    if (t < 8) {
        int running = 0;
        for (int q = 0; q < 256; ++q) {
            int c = hist[q][t];
            hist[q][t] = running;   // exclusive prefix, in place
            running += c;
        }
        totals[t] = running;
        psum[t] = pred[0][t] + pred[1][t] + pred[2][t] + pred[3][t];
    }
    __syncthreads();

    int run[8];
    #pragma unroll
    for (int e = 0; e < 8; ++e) run[e] = hist[t][e];
    #pragma unroll
    for (int k = 0; k < 16; ++k) {
        int n = t * 16 + k;
        int e = myE[k];
        int r = run[e]++;
        gates[n] = (r < CCAP) ? probs[(size_t)n * 8 + e] : 0.0f;
    }

    if (t == 0) {
        float aux = 0.f;
        #pragma unroll
        for (int e = 0; e < 8; ++e) {
            float fe = (float)min(totals[e], CCAP) * (1.0f / 4096.0f);
            float pe = psum[e] * (1.0f / 4096.0f);
            aux += fe * pe;
        }
        out_aux[0] = 8.0f * aux;
    }
}

// ---------------------------------------------------------------------------
// Kernel 3: per-patch 3x3 SAME conv (3->8 ch, zero-padded per patch), bias,
// ReLU, per-output-channel pixel sum, times gate. One block per patch.
// ---------------------------------------------------------------------------
__global__ __launch_bounds__(256) void k_conv(const float* __restrict__ X,
        const float* __restrict__ ew, const float* __restrict__ eb,
        const int* __restrict__ eidx, const float* __restrict__ gates,
        float* __restrict__ znc)
{
    int n = blockIdx.x;
    int b = n >> 8, p = n & 255, pr = p >> 4, pc = p & 15;
    int tid = threadIdx.x;
    int i = tid >> 4, j = tid & 15;

    __shared__ float s[3][18][18];
    __shared__ float wsm[216];
    __shared__ float bsm[8];
    __shared__ int esh;
    __shared__ float gsh;

    if (tid == 0) { esh = eidx[n]; gsh = gates[n]; }
    float* sf = &s[0][0][0];
    for (int idx = tid; idx < 3 * 18 * 18; idx += 256) sf[idx] = 0.f;
    __syncthreads();

    int e = esh;
    for (int idx = tid; idx < 216; idx += 256) wsm[idx] = ew[e * 216 + idx];
    if (tid < 8) bsm[tid] = eb[e * 8 + tid];
    #pragma unroll
    for (int c = 0; c < 3; ++c)
        s[c][i + 1][j + 1] =
            X[((size_t)(b * 3 + c) * 256 + pr * 16 + i) * 256 + pc * 16 + j];
    __syncthreads();

    float y[8];
    #pragma unroll
    for (int co = 0; co < 8; ++co) {
        float acc = bsm[co];
        #pragma unroll
        for (int ci = 0; ci < 3; ++ci)
            #pragma unroll
            for (int di = 0; di < 3; ++di)
                #pragma unroll
                for (int dj = 0; dj < 3; ++dj)
                    acc += s[ci][i + di][j + dj] * wsm[co * 27 + ci * 9 + di * 3 + dj];
        y[co] = fmaxf(acc, 0.f);
    }

    __shared__ float red[4][8];
    int wave = tid >> 6, lane = tid & 63;
    #pragma unroll
    for (int co = 0; co < 8; ++co) {
        float v = waveReduceSum(y[co]);
        if (lane == 0) red[wave][co] = v;
    }
    __syncthreads();
    if (tid < 8)
        znc[(size_t)n * 8 + tid] =
            gsh * (red[0][tid] + red[1][tid] + red[2][tid] + red[3][tid]);
}

// ---------------------------------------------------------------------------
// Kernel 4: feat[b][512] from znc (2x2 patch pool / 1024), then
// logits_cls[b][k] = feat @ lin_w + lin_b. Grid (16 batches, 8 col-chunks),
// 128 threads; thread = one output column.
// ---------------------------------------------------------------------------
__global__ __launch_bounds__(128) void k_cls(const float* __restrict__ znc,
        const float* __restrict__ lw, const float* __restrict__ lb,
        float* __restrict__ out)
{
    int b = blockIdx.x;
    int chunk = blockIdx.y;
    int tid = threadIdx.x;
    __shared__ float feat[512];

    for (int f = tid; f < 512; f += 128) {
        int co = f >> 6, rem = f & 63, py = rem >> 3, px = rem & 7;
        float sum = 0.f;
        #pragma unroll
        for (int dy = 0; dy < 2; ++dy)
            #pragma unroll
            for (int dx = 0; dx < 2; ++dx) {
                int n = b * 256 + (2 * py + dy) * 16 + (2 * px + dx);
                sum += znc[(size_t)n * 8 + co];
            }
        feat[f] = sum * (1.0f / 1024.0f);
    }
    __syncthreads();

    int k = chunk * 125 + tid;
    if (tid < 125) {
        float acc = lb[k];
        #pragma unroll 8
        for (int f = 0; f < 512; ++f) acc += feat[f] * lw[(size_t)f * 1000 + k];
        out[b * 1000 + k] = acc;
    }
}

extern "C" void kernel_launch(void* const* d_in, const int* in_sizes, int n_in,
                              void* d_out, int out_size, void* d_ws, size_t ws_size,
                              hipStream_t stream) {
    const float* X  = (const float*)d_in[0];
    const float* ew = (const float*)d_in[1];
    const float* eb = (const float*)d_in[2];
    const float* gw = (const float*)d_in[3];
    const float* gb = (const float*)d_in[4];
    const float* lw = (const float*)d_in[5];
    const float* lb = (const float*)d_in[6];
    float* out = (float*)d_out;

    char* ws = (char*)d_ws;
    int*   eidx  = (int*)  (ws + 0);                       // 4096 ints
    float* probs = (float*)(ws + 4096 * 4);                // 4096*8 floats
    float* gates = (float*)(ws + 4096 * 4 + 4096 * 32);    // 4096 floats
    float* znc   = (float*)(ws + 4096 * 4 + 4096 * 36);    // 4096*8 floats

    k_gate<<<4096, 256, 0, stream>>>(X, gw, gb, eidx, probs);
    k_rank<<<1, 256, 0, stream>>>(eidx, probs, gates, out + 16000);
    k_conv<<<4096, 256, 0, stream>>>(X, ew, eb, eidx, gates, znc);
    k_cls<<<dim3(16, 8), 128, 0, stream>>>(znc, lw, lb, out);
}

// Round 3
// 142.641 us; speedup vs baseline: 4.5117x; 1.2512x over previous
//
#include <hip/hip_runtime.h>
#include <math.h>

#define CCAP 640
#define TWO_PI 6.28318530717958647692f

// ---------------------------------------------------------------------------
// Kernel 1: gating. One block per (b, pr) stripe: 3 channels x 16 rows x 256
// cols of X. Computes the 3 per-patch image-channel sums (pure BW), then 16
// threads (one per pc) compute the 20 positional-channel sums analytically
// (separable 1-D sums), the 8 logits, softmax, argmax. Writes eidx[n],
// ptop[n], and per-block expert prob-sum partials (no atomics).
// ---------------------------------------------------------------------------
__global__ __launch_bounds__(256) void k_gate(const float* __restrict__ X,
        const float* __restrict__ gw, const float* __restrict__ gb,
        int* __restrict__ eidx, float* __restrict__ ptop,
        float* __restrict__ pspart)
{
    int blk = blockIdx.x;           // 0..255
    int b = blk >> 4, pr = blk & 15;
    int t = threadIdx.x;
    int wave = t >> 6, lane = t & 63;
    int pc_of_lane = lane >> 2;     // lanes 4k..4k+3 share pc

    // ---- image channel sums over the stripe (coalesced float4) ----
    float part[3] = {0.f, 0.f, 0.f};
    #pragma unroll
    for (int c = 0; c < 3; ++c) {
        const float4* base =
            (const float4*)(X + ((size_t)(b * 3 + c) * 256 + pr * 16) * 256);
        #pragma unroll
        for (int m = 0; m < 4; ++m) {
            float4 v = base[t + 256 * m];   // q = t+256m; pc = (q&63)>>2 const
            part[c] += (v.x + v.y) + (v.z + v.w);
        }
    }

    __shared__ float red[4][16][3];
    #pragma unroll
    for (int c = 0; c < 3; ++c) {
        float v = part[c];
        v += __shfl_xor(v, 1, 64);
        v += __shfl_xor(v, 2, 64);
        if ((lane & 3) == 0) red[wave][pc_of_lane][c] = v;
    }
    __syncthreads();

    if (t < 16) {
        int pc = t;
        int n = b * 256 + pr * 16 + pc;

        float S[23];
        #pragma unroll
        for (int c = 0; c < 3; ++c)
            S[c] = red[0][pc][c] + red[1][pc][c] + red[2][pc][c] + red[3][pc][c];

        // separable positional sums
        float Sgx1 = 0.f, Cgx1 = 0.f, Sgx2 = 0.f, Cgx2 = 0.f;
        float Sgy1 = 0.f, Cgy1 = 0.f, Sgy2 = 0.f, Cgy2 = 0.f;
        for (int j = 0; j < 16; ++j) {
            float tx = (float)(pc * 16 + j) * (1.0f / 256.0f);
            float ty = (float)(pr * 16 + j) * (1.0f / 256.0f);
            Sgx1 += sinf(TWO_PI * tx);        Cgx1 += cosf(TWO_PI * tx);
            Sgx2 += sinf(2.f * TWO_PI * tx);  Cgx2 += cosf(2.f * TWO_PI * tx);
            Sgy1 += sinf(TWO_PI * ty);        Cgy1 += cosf(TWO_PI * ty);
            Sgy2 += sinf(2.f * TWO_PI * ty);  Cgy2 += cosf(2.f * TWO_PI * ty);
        }
        float pcx = ((float)pc + 0.5f) * (1.0f / 16.0f);
        float pcy = ((float)pr + 0.5f) * (1.0f / 16.0f);

        S[3] = 16.f * ((float)pc + 0.46875f);   // sum gx
        S[4] = 16.f * ((float)pr + 0.46875f);   // sum gy
        S[5] = 256.f * pcx;                     // sum pcx
        S[6] = 256.f * pcy;                     // sum pcy
        S[7]  = 16.f * Sgx1;  S[8]  = 16.f * Cgx1;
        S[9]  = 16.f * Sgy1;  S[10] = 16.f * Cgy1;
        S[11] = 256.f * sinf(TWO_PI * pcx);  S[12] = 256.f * cosf(TWO_PI * pcx);
        S[13] = 256.f * sinf(TWO_PI * pcy);  S[14] = 256.f * cosf(TWO_PI * pcy);
        S[15] = 16.f * Sgx2;  S[16] = 16.f * Cgx2;
        S[17] = 16.f * Sgy2;  S[18] = 16.f * Cgy2;
        S[19] = 256.f * sinf(2.f * TWO_PI * pcx);  S[20] = 256.f * cosf(2.f * TWO_PI * pcx);
        S[21] = 256.f * sinf(2.f * TWO_PI * pcy);  S[22] = 256.f * cosf(2.f * TWO_PI * pcy);

        float lg[8];
        float mx = -1e30f;
        #pragma unroll
        for (int e = 0; e < 8; ++e) {
            float acc = 0.f;
            #pragma unroll
            for (int c = 0; c < 23; ++c) acc += S[c] * gw[e * 23 + c];
            lg[e] = acc * (1.0f / 256.0f) + gb[e];
            mx = fmaxf(mx, lg[e]);
        }
        float den = 0.f;
        float prob[8];
        #pragma unroll
        for (int e = 0; e < 8; ++e) { prob[e] = expf(lg[e] - mx); den += prob[e]; }
        float invden = 1.0f / den;
        #pragma unroll
        for (int e = 0; e < 8; ++e) prob[e] *= invden;

        int am = 0; float best = lg[0];
        #pragma unroll
        for (int e = 1; e < 8; ++e) if (lg[e] > best) { best = lg[e]; am = e; }
        eidx[n] = am;
        ptop[n] = prob[am];

        // block-partial per-expert prob sums (reduce over the 16 active lanes)
        #pragma unroll
        for (int e = 0; e < 8; ++e) {
            float v = prob[e];
            v += __shfl_xor(v, 1, 64);
            v += __shfl_xor(v, 2, 64);
            v += __shfl_xor(v, 4, 64);
            v += __shfl_xor(v, 8, 64);
            if (t == 0) pspart[blk * 8 + e] = v;
        }
    }
}

// ---------------------------------------------------------------------------
// Kernel 2: ordered per-expert rank (cumsum semantics), capacity mask, gates,
// psum reduction, aux loss. One block, 256 threads, thread owns 16 consecutive n.
// ---------------------------------------------------------------------------
__global__ __launch_bounds__(256) void k_route(const int* __restrict__ eidx,
        const float* __restrict__ ptop, const float* __restrict__ pspart,
        float* __restrict__ gates, float* __restrict__ out_aux)
{
    __shared__ int hist[256][8];
    __shared__ int totals[8];
    __shared__ float pred[4][8];
    __shared__ float psum[8];
    int t = threadIdx.x;
    int wave = t >> 6, lane = t & 63;

    int h[8] = {0, 0, 0, 0, 0, 0, 0, 0};
    int myE[16];
    #pragma unroll
    for (int k = 0; k < 16; ++k) {
        int e = eidx[t * 16 + k];
        myE[k] = e;
        h[e]++;
    }
    #pragma unroll
    for (int e = 0; e < 8; ++e) hist[t][e] = h[e];

    #pragma unroll
    for (int e = 0; e < 8; ++e) {
        float v = pspart[t * 8 + e];
        #pragma unroll
        for (int off = 32; off >= 1; off >>= 1) v += __shfl_down(v, off, 64);
        if (lane == 0) pred[wave][e] = v;
    }
    __syncthreads();

    if (t < 8) {
        int running = 0;
        for (int q = 0; q < 256; ++q) {
            int c = hist[q][t];
            hist[q][t] = running;   // exclusive prefix, in place
            running += c;
        }
        totals[t] = running;
        psum[t] = pred[0][t] + pred[1][t] + pred[2][t] + pred[3][t];
    }
    __syncthreads();

    int run[8];
    #pragma unroll
    for (int e = 0; e < 8; ++e) run[e] = hist[t][e];
    #pragma unroll
    for (int k = 0; k < 16; ++k) {
        int n = t * 16 + k;
        int e = myE[k];
        int r = run[e]++;
        gates[n] = (r < CCAP) ? ptop[n] : 0.0f;
    }

    if (t == 0) {
        float aux = 0.f;
        #pragma unroll
        for (int e = 0; e < 8; ++e) {
            float fe = (float)min(totals[e], CCAP) * (1.0f / 4096.0f);
            float pe = psum[e] * (1.0f / 4096.0f);
            aux += fe * pe;
        }
        out_aux[0] = 8.0f * aux;
    }
}

// ---------------------------------------------------------------------------
// Kernel 3: per-patch 3x3 SAME conv (3->8 ch, zero-padded per patch), bias,
// ReLU, per-output-channel pixel sum, times gate. One block per patch.
// Weights/bias/gate via block-uniform (scalar) loads; window in registers.
// ---------------------------------------------------------------------------
__global__ __launch_bounds__(256) void k_conv(const float* __restrict__ X,
        const float* __restrict__ ew, const float* __restrict__ eb,
        const int* __restrict__ eidx, const float* __restrict__ gates,
        float* __restrict__ znc)
{
    int n = blockIdx.x;
    int b = n >> 8, p = n & 255, pr = p >> 4, pc = p & 15;
    int tid = threadIdx.x;
    int i = tid >> 4, j = tid & 15;

    int   e = eidx[n];    // uniform -> scalar load
    float g = gates[n];   // uniform -> scalar load
    const float* w = ew + (size_t)e * 216;

    __shared__ float s[3][18][18];
    float* sf = &s[0][0][0];
    for (int idx = tid; idx < 3 * 18 * 18; idx += 256) sf[idx] = 0.f;
    __syncthreads();

    #pragma unroll
    for (int c = 0; c < 3; ++c)
        s[c][i + 1][j + 1] =
            X[((size_t)(b * 3 + c) * 256 + pr * 16 + i) * 256 + pc * 16 + j];
    __syncthreads();

    float acc[8];
    #pragma unroll
    for (int co = 0; co < 8; ++co) acc[co] = eb[e * 8 + co];

    #pragma unroll
    for (int ci = 0; ci < 3; ++ci)
        #pragma unroll
        for (int di = 0; di < 3; ++di)
            #pragma unroll
            for (int dj = 0; dj < 3; ++dj) {
                float v = s[ci][i + di][j + dj];
                #pragma unroll
                for (int co = 0; co < 8; ++co)
                    acc[co] += v * w[co * 27 + ci * 9 + di * 3 + dj];
            }

    __shared__ float red[4][8];
    int wave = tid >> 6, lane = tid & 63;
    #pragma unroll
    for (int co = 0; co < 8; ++co) {
        float v = fmaxf(acc[co], 0.f);
        #pragma unroll
        for (int off = 32; off >= 1; off >>= 1) v += __shfl_down(v, off, 64);
        if (lane == 0) red[wave][co] = v;
    }
    __syncthreads();
    if (tid < 8)
        znc[(size_t)n * 8 + tid] =
            g * (red[0][tid] + red[1][tid] + red[2][tid] + red[3][tid]);
}

// ---------------------------------------------------------------------------
// Kernel 4: feat[b][512] from znc (2x2 patch pool / 1024), then
// logits_cls[b][k] = feat @ lin_w + lin_b. Grid (16 batches, 8 col-chunks).
// ---------------------------------------------------------------------------
__global__ __launch_bounds__(128) void k_cls(const float* __restrict__ znc,
        const float* __restrict__ lw, const float* __restrict__ lb,
        float* __restrict__ out)
{
    int b = blockIdx.x;
    int chunk = blockIdx.y;
    int tid = threadIdx.x;
    __shared__ float feat[512];

    for (int f = tid; f < 512; f += 128) {
        int co = f >> 6, rem = f & 63, py = rem >> 3, px = rem & 7;
        float sum = 0.f;
        #pragma unroll
        for (int dy = 0; dy < 2; ++dy)
            #pragma unroll
            for (int dx = 0; dx < 2; ++dx) {
                int nn = b * 256 + (2 * py + dy) * 16 + (2 * px + dx);
                sum += znc[(size_t)nn * 8 + co];
            }
        feat[f] = sum * (1.0f / 1024.0f);
    }
    __syncthreads();

    int k = chunk * 125 + tid;
    if (tid < 125) {
        float acc = lb[k];
        #pragma unroll 8
        for (int f = 0; f < 512; ++f) acc += feat[f] * lw[(size_t)f * 1000 + k];
        out[b * 1000 + k] = acc;
    }
}

extern "C" void kernel_launch(void* const* d_in, const int* in_sizes, int n_in,
                              void* d_out, int out_size, void* d_ws, size_t ws_size,
                              hipStream_t stream) {
    const float* X  = (const float*)d_in[0];
    const float* ew = (const float*)d_in[1];
    const float* eb = (const float*)d_in[2];
    const float* gw = (const float*)d_in[3];
    const float* gb = (const float*)d_in[4];
    const float* lw = (const float*)d_in[5];
    const float* lb = (const float*)d_in[6];
    float* out = (float*)d_out;

    char* ws = (char*)d_ws;
    int*   eidx   = (int*)  (ws + 0);                    // 4096 ints
    float* ptop   = (float*)(ws + 16384);                // 4096 floats
    float* pspart = (float*)(ws + 32768);                // 256*8 floats
    float* gates  = (float*)(ws + 40960);                // 4096 floats
    float* znc    = (float*)(ws + 57344);                // 4096*8 floats

    k_gate<<<256, 256, 0, stream>>>(X, gw, gb, eidx, ptop, pspart);
    k_route<<<1, 256, 0, stream>>>(eidx, ptop, pspart, gates, out + 16000);
    k_conv<<<4096, 256, 0, stream>>>(X, ew, eb, eidx, gates, znc);
    k_cls<<<dim3(16, 8), 128, 0, stream>>>(znc, lw, lb, out);
}

// Round 4
// 138.422 us; speedup vs baseline: 4.6492x; 1.0305x over previous
//
#include <hip/hip_runtime.h>
#include <math.h>

#define CCAP 640
#define TWO_PI 6.28318530717958647692f

__device__ __forceinline__ float waveReduceSum(float v) {
    #pragma unroll
    for (int off = 32; off >= 1; off >>= 1) v += __shfl_down(v, off, 64);
    return v;
}

// ---------------------------------------------------------------------------
// Kernel 1 (fused gate+conv): one block per patch.
//  - stage 3x16x16 patch into padded LDS (single X read for the whole net)
//  - wave-reduce the 3 image-channel sums
//  - lanes 0..15 compute separable trig sums; thread 0 does logits -> softmax
//    -> argmax (identical formulas to the verified round-3 k_gate)
//  - all threads conv 3x3 SAME (patch-local zero pad) with the chosen expert,
//    ReLU, per-output-channel pixel sums -> snc[n][8] (UNSCALED; the gate is
//    applied in k_cls since scaling commutes with pooling)
// ---------------------------------------------------------------------------
__global__ __launch_bounds__(256) void k_fused(const float* __restrict__ X,
        const float* __restrict__ gw, const float* __restrict__ gb,
        const float* __restrict__ ew, const float* __restrict__ eb,
        int* __restrict__ eidx, float* __restrict__ probs,
        float* __restrict__ snc)
{
    int n = blockIdx.x;
    int b = n >> 8, p = n & 255, pr = p >> 4, pc = p & 15;
    int tid = threadIdx.x;
    int i = tid >> 4, j = tid & 15;
    int wave = tid >> 6, lane = tid & 63;

    __shared__ float s[3][18][18];
    __shared__ float redc[4][3];
    __shared__ float trig[8];
    __shared__ int esh;

    float* sf = &s[0][0][0];
    for (int idx = tid; idx < 3 * 18 * 18; idx += 256) sf[idx] = 0.f;
    __syncthreads();

    float px[3];
    #pragma unroll
    for (int c = 0; c < 3; ++c) {
        px[c] = X[((size_t)(b * 3 + c) * 256 + pr * 16 + i) * 256 + pc * 16 + j];
        s[c][i + 1][j + 1] = px[c];
    }

    // image channel sums (for gating)
    #pragma unroll
    for (int c = 0; c < 3; ++c) {
        float v = waveReduceSum(px[c]);
        if (lane == 0) redc[wave][c] = v;
    }

    // separable 1-D trig sums: lane t handles j = t
    if (tid < 16) {
        float tx = (float)(pc * 16 + tid) * (1.0f / 256.0f);
        float ty = (float)(pr * 16 + tid) * (1.0f / 256.0f);
        float v0 = sinf(TWO_PI * tx),       v1 = cosf(TWO_PI * tx);
        float v2 = sinf(2.f * TWO_PI * tx), v3 = cosf(2.f * TWO_PI * tx);
        float v4 = sinf(TWO_PI * ty),       v5 = cosf(TWO_PI * ty);
        float v6 = sinf(2.f * TWO_PI * ty), v7 = cosf(2.f * TWO_PI * ty);
        #pragma unroll
        for (int off = 8; off >= 1; off >>= 1) {
            v0 += __shfl_xor(v0, off, 64);
            v1 += __shfl_xor(v1, off, 64);
            v2 += __shfl_xor(v2, off, 64);
            v3 += __shfl_xor(v3, off, 64);
            v4 += __shfl_xor(v4, off, 64);
            v5 += __shfl_xor(v5, off, 64);
            v6 += __shfl_xor(v6, off, 64);
            v7 += __shfl_xor(v7, off, 64);
        }
        if (tid == 0) {
            trig[0] = v0; trig[1] = v1; trig[2] = v2; trig[3] = v3;
            trig[4] = v4; trig[5] = v5; trig[6] = v6; trig[7] = v7;
        }
    }
    __syncthreads();

    if (tid == 0) {
        float pcx = ((float)pc + 0.5f) * (1.0f / 16.0f);
        float pcy = ((float)pr + 0.5f) * (1.0f / 16.0f);

        float S[23];
        #pragma unroll
        for (int c = 0; c < 3; ++c)
            S[c] = redc[0][c] + redc[1][c] + redc[2][c] + redc[3][c];
        S[3] = 16.f * ((float)pc + 0.46875f);
        S[4] = 16.f * ((float)pr + 0.46875f);
        S[5] = 256.f * pcx;
        S[6] = 256.f * pcy;
        S[7]  = 16.f * trig[0];  S[8]  = 16.f * trig[1];
        S[9]  = 16.f * trig[4];  S[10] = 16.f * trig[5];
        S[11] = 256.f * sinf(TWO_PI * pcx);  S[12] = 256.f * cosf(TWO_PI * pcx);
        S[13] = 256.f * sinf(TWO_PI * pcy);  S[14] = 256.f * cosf(TWO_PI * pcy);
        S[15] = 16.f * trig[2];  S[16] = 16.f * trig[3];
        S[17] = 16.f * trig[6];  S[18] = 16.f * trig[7];
        S[19] = 256.f * sinf(2.f * TWO_PI * pcx);  S[20] = 256.f * cosf(2.f * TWO_PI * pcx);
        S[21] = 256.f * sinf(2.f * TWO_PI * pcy);  S[22] = 256.f * cosf(2.f * TWO_PI * pcy);

        float lg[8];
        float mx = -1e30f;
        #pragma unroll
        for (int e = 0; e < 8; ++e) {
            float acc = 0.f;
            #pragma unroll
            for (int c = 0; c < 23; ++c) acc += S[c] * gw[e * 23 + c];
            lg[e] = acc * (1.0f / 256.0f) + gb[e];
            mx = fmaxf(mx, lg[e]);
        }
        float den = 0.f;
        float prob[8];
        #pragma unroll
        for (int e = 0; e < 8; ++e) { prob[e] = expf(lg[e] - mx); den += prob[e]; }
        float invden = 1.0f / den;
        int am = 0; float best = lg[0];
        #pragma unroll
        for (int e = 1; e < 8; ++e) if (lg[e] > best) { best = lg[e]; am = e; }
        esh = am;
        eidx[n] = am;
        #pragma unroll
        for (int e = 0; e < 8; ++e) probs[(size_t)n * 8 + e] = prob[e] * invden;
    }
    __syncthreads();

    int e = esh;                       // block-uniform
    const float* w = ew + (size_t)e * 216;

    float acc[8];
    #pragma unroll
    for (int co = 0; co < 8; ++co) acc[co] = eb[e * 8 + co];

    #pragma unroll
    for (int ci = 0; ci < 3; ++ci)
        #pragma unroll
        for (int di = 0; di < 3; ++di)
            #pragma unroll
            for (int dj = 0; dj < 3; ++dj) {
                float v = s[ci][i + di][j + dj];
                #pragma unroll
                for (int co = 0; co < 8; ++co)
                    acc[co] += v * w[co * 27 + ci * 9 + di * 3 + dj];
            }

    __shared__ float red[4][8];
    #pragma unroll
    for (int co = 0; co < 8; ++co) {
        float v = fmaxf(acc[co], 0.f);
        v = waveReduceSum(v);
        if (lane == 0) red[wave][co] = v;
    }
    __syncthreads();
    if (tid < 8)
        snc[(size_t)n * 8 + tid] =
            red[0][tid] + red[1][tid] + red[2][tid] + red[3][tid];
}

// ---------------------------------------------------------------------------
// Kernel 2: ordered per-expert rank (cumsum semantics), capacity mask, gates,
// prob-sum reduction, aux loss. One block, 256 threads x 16 consecutive n.
// ---------------------------------------------------------------------------
__global__ __launch_bounds__(256) void k_route(const int* __restrict__ eidx,
        const float* __restrict__ probs, float* __restrict__ gates,
        float* __restrict__ out_aux)
{
    __shared__ int hist[256][8];
    __shared__ int totals[8];
    __shared__ float pred[4][8];
    __shared__ float psum[8];
    int t = threadIdx.x;
    int wave = t >> 6, lane = t & 63;

    int h[8] = {0, 0, 0, 0, 0, 0, 0, 0};
    float lp[8] = {0.f, 0.f, 0.f, 0.f, 0.f, 0.f, 0.f, 0.f};
    int myE[16];
    #pragma unroll
    for (int k = 0; k < 16; ++k) {
        int n = t * 16 + k;
        int e = eidx[n];
        myE[k] = e;
        h[e]++;
        #pragma unroll
        for (int q = 0; q < 8; ++q) lp[q] += probs[(size_t)n * 8 + q];
    }
    #pragma unroll
    for (int e = 0; e < 8; ++e) hist[t][e] = h[e];
    #pragma unroll
    for (int e = 0; e < 8; ++e) {
        float v = waveReduceSum(lp[e]);
        if (lane == 0) pred[wave][e] = v;
    }
    __syncthreads();

    if (t < 8) {
        int running = 0;
        for (int q = 0; q < 256; ++q) {
            int c = hist[q][t];
            hist[q][t] = running;   // exclusive prefix, in place
            running += c;
        }
        totals[t] = running;
        psum[t] = pred[0][t] + pred[1][t] + pred[2][t] + pred[3][t];
    }
    __syncthreads();

    int run[8];
    #pragma unroll
    for (int e = 0; e < 8; ++e) run[e] = hist[t][e];
    #pragma unroll
    for (int k = 0; k < 16; ++k) {
        int n = t * 16 + k;
        int e = myE[k];
        int r = run[e]++;
        gates[n] = (r < CCAP) ? probs[(size_t)n * 8 + e] : 0.0f;
    }

    if (t == 0) {
        float aux = 0.f;
        #pragma unroll
        for (int e = 0; e < 8; ++e) {
            float fe = (float)min(totals[e], CCAP) * (1.0f / 4096.0f);
            float pe = psum[e] * (1.0f / 4096.0f);
            aux += fe * pe;
        }
        out_aux[0] = 8.0f * aux;
    }
}

// ---------------------------------------------------------------------------
// Kernel 3: feat[b][512] from gate-scaled snc (2x2 patch pool / 1024), then
// logits_cls[b][k] = feat @ lin_w + lin_b. Grid (16 batches, 8 col-chunks).
// ---------------------------------------------------------------------------
__global__ __launch_bounds__(128) void k_cls(const float* __restrict__ snc,
        const float* __restrict__ gates, const float* __restrict__ lw,
        const float* __restrict__ lb, float* __restrict__ out)
{
    int b = blockIdx.x;
    int chunk = blockIdx.y;
    int tid = threadIdx.x;
    __shared__ float feat[512];

    for (int f = tid; f < 512; f += 128) {
        int co = f >> 6, rem = f & 63, py = rem >> 3, px = rem & 7;
        float sum = 0.f;
        #pragma unroll
        for (int dy = 0; dy < 2; ++dy)
            #pragma unroll
            for (int dx = 0; dx < 2; ++dx) {
                int nn = b * 256 + (2 * py + dy) * 16 + (2 * px + dx);
                sum += gates[nn] * snc[(size_t)nn * 8 + co];
            }
        feat[f] = sum * (1.0f / 1024.0f);
    }
    __syncthreads();

    int k = chunk * 125 + tid;
    if (tid < 125) {
        float acc = lb[k];
        #pragma unroll 8
        for (int f = 0; f < 512; ++f) acc += feat[f] * lw[(size_t)f * 1000 + k];
        out[b * 1000 + k] = acc;
    }
}

extern "C" void kernel_launch(void* const* d_in, const int* in_sizes, int n_in,
                              void* d_out, int out_size, void* d_ws, size_t ws_size,
                              hipStream_t stream) {
    const float* X  = (const float*)d_in[0];
    const float* ew = (const float*)d_in[1];
    const float* eb = (const float*)d_in[2];
    const float* gw = (const float*)d_in[3];
    const float* gb = (const float*)d_in[4];
    const float* lw = (const float*)d_in[5];
    const float* lb = (const float*)d_in[6];
    float* out = (float*)d_out;

    char* ws = (char*)d_ws;
    int*   eidx  = (int*)  (ws + 0);            // 4096 ints      (16 KB)
    float* probs = (float*)(ws + 16384);        // 4096*8 floats  (128 KB)
    float* gates = (float*)(ws + 16384 + 131072);           // 4096 floats
    float* snc   = (float*)(ws + 16384 + 131072 + 16384);   // 4096*8 floats

    k_fused<<<4096, 256, 0, stream>>>(X, gw, gb, ew, eb, eidx, probs, snc);
    k_route<<<1, 256, 0, stream>>>(eidx, probs, gates, out + 16000);
    k_cls<<<dim3(16, 8), 128, 0, stream>>>(snc, gates, lw, lb, out);
}

// Round 5
// 114.702 us; speedup vs baseline: 5.6107x; 1.2068x over previous
//
#include <hip/hip_runtime.h>
#include <math.h>

#define CCAP 640
#define TWO_PI 6.28318530717958647692f

// ---------------------------------------------------------------------------
// Kernel 1 (fused gate+conv, register-only): ONE WAVE PER PATCH.
// Lane layout: i = lane>>2 (row 0..15), q = lane&3 (cols 4q..4q+3).
// - 3x float4 global load (only X read in the whole net)
// - gating sums via butterfly shuffles; ALL lanes compute identical
//   logits/softmax/argmax (deterministic) -> readfirstlane(e) -> scalar
//   weight loads
// - 3x3 SAME conv (patch-local zero pad) with halo via __shfl (no LDS),
//   ReLU, per-channel sums via butterfly -> snc[n][8] (unscaled)
// ---------------------------------------------------------------------------
__global__ __launch_bounds__(256) void k_fused(const float* __restrict__ X,
        const float* __restrict__ gw, const float* __restrict__ gb,
        const float* __restrict__ ew, const float* __restrict__ eb,
        int* __restrict__ eidx, float* __restrict__ probs,
        float* __restrict__ snc)
{
    int tid = threadIdx.x;
    int wave = tid >> 6, lane = tid & 63;
    int n = blockIdx.x * 4 + wave;
    int b = n >> 8, p = n & 255, pr = p >> 4, pc = p & 15;
    int i = lane >> 2, q = lane & 3;

    // ---- load: per-channel float4 strip (cols 4q..4q+3 of row i) ----
    float4 px[3];
    #pragma unroll
    for (int c = 0; c < 3; ++c)
        px[c] = *(const float4*)(X +
            ((size_t)(b * 3 + c) * 256 + pr * 16 + i) * 256 + pc * 16 + q * 4);

    // ---- channel sums (full-wave butterfly -> every lane has total) ----
    float S0, S1, S2;
    {
        float s0 = (px[0].x + px[0].y) + (px[0].z + px[0].w);
        float s1 = (px[1].x + px[1].y) + (px[1].z + px[1].w);
        float s2 = (px[2].x + px[2].y) + (px[2].z + px[2].w);
        #pragma unroll
        for (int off = 1; off < 64; off <<= 1) {
            s0 += __shfl_xor(s0, off, 64);
            s1 += __shfl_xor(s1, off, 64);
            s2 += __shfl_xor(s2, off, 64);
        }
        S0 = s0; S1 = s1; S2 = s2;
    }

    // ---- separable trig sums: lane handles column/row m = lane&15 ----
    int m = lane & 15;
    float tx = (float)(pc * 16 + m) * (1.0f / 256.0f);
    float ty = (float)(pr * 16 + m) * (1.0f / 256.0f);
    float t0 = __sinf(TWO_PI * tx),       t1 = __cosf(TWO_PI * tx);
    float t2 = __sinf(2.f * TWO_PI * tx), t3 = __cosf(2.f * TWO_PI * tx);
    float t4 = __sinf(TWO_PI * ty),       t5 = __cosf(TWO_PI * ty);
    float t6 = __sinf(2.f * TWO_PI * ty), t7 = __cosf(2.f * TWO_PI * ty);
    #pragma unroll
    for (int off = 1; off < 16; off <<= 1) {
        t0 += __shfl_xor(t0, off, 64);  t1 += __shfl_xor(t1, off, 64);
        t2 += __shfl_xor(t2, off, 64);  t3 += __shfl_xor(t3, off, 64);
        t4 += __shfl_xor(t4, off, 64);  t5 += __shfl_xor(t5, off, 64);
        t6 += __shfl_xor(t6, off, 64);  t7 += __shfl_xor(t7, off, 64);
    }

    // ---- logits -> softmax -> argmax (replicated on all 64 lanes) ----
    float pcx = ((float)pc + 0.5f) * (1.0f / 16.0f);
    float pcy = ((float)pr + 0.5f) * (1.0f / 16.0f);
    float S[23];
    S[0] = S0; S[1] = S1; S[2] = S2;
    S[3] = 16.f * ((float)pc + 0.46875f);
    S[4] = 16.f * ((float)pr + 0.46875f);
    S[5] = 256.f * pcx;  S[6] = 256.f * pcy;
    S[7]  = 16.f * t0;  S[8]  = 16.f * t1;
    S[9]  = 16.f * t4;  S[10] = 16.f * t5;
    S[11] = 256.f * __sinf(TWO_PI * pcx);  S[12] = 256.f * __cosf(TWO_PI * pcx);
    S[13] = 256.f * __sinf(TWO_PI * pcy);  S[14] = 256.f * __cosf(TWO_PI * pcy);
    S[15] = 16.f * t2;  S[16] = 16.f * t3;
    S[17] = 16.f * t6;  S[18] = 16.f * t7;
    S[19] = 256.f * __sinf(2.f * TWO_PI * pcx);  S[20] = 256.f * __cosf(2.f * TWO_PI * pcx);
    S[21] = 256.f * __sinf(2.f * TWO_PI * pcy);  S[22] = 256.f * __cosf(2.f * TWO_PI * pcy);

    float lg[8];
    float mx = -1e30f;
    #pragma unroll
    for (int ee = 0; ee < 8; ++ee) {
        float a = 0.f;
        #pragma unroll
        for (int c = 0; c < 23; ++c) a += S[c] * gw[ee * 23 + c];
        lg[ee] = a * (1.0f / 256.0f) + gb[ee];
        mx = fmaxf(mx, lg[ee]);
    }
    float den = 0.f;
    float prob[8];
    #pragma unroll
    for (int ee = 0; ee < 8; ++ee) { prob[ee] = __expf(lg[ee] - mx); den += prob[ee]; }
    float inv = 1.0f / den;
    #pragma unroll
    for (int ee = 0; ee < 8; ++ee) prob[ee] *= inv;
    int am = 0; float best = lg[0];
    #pragma unroll
    for (int ee = 1; ee < 8; ++ee) if (lg[ee] > best) { best = lg[ee]; am = ee; }

    int e = __builtin_amdgcn_readfirstlane(am);
    const float* wp = ew + (size_t)e * 216;

    // ---- conv 3x3 SAME, halo via shuffles, weights scalar ----
    float acc[8][4];
    #pragma unroll
    for (int co = 0; co < 8; ++co) {
        float bv = eb[e * 8 + co];
        #pragma unroll
        for (int k = 0; k < 4; ++k) acc[co][k] = bv;
    }

    #pragma unroll
    for (int ci = 0; ci < 3; ++ci) {
        float4 v = px[ci];
        float own[6];
        own[1] = v.x; own[2] = v.y; own[3] = v.z; own[4] = v.w;
        float L = __shfl(v.w, lane - 1, 64);
        float R = __shfl(v.x, lane + 1, 64);
        own[0] = (q == 0) ? 0.f : L;
        own[5] = (q == 3) ? 0.f : R;
        float up[6], dn[6];
        #pragma unroll
        for (int c6 = 0; c6 < 6; ++c6) {
            float u = __shfl(own[c6], lane - 4, 64);
            float d = __shfl(own[c6], lane + 4, 64);
            up[c6] = (i == 0)  ? 0.f : u;
            dn[c6] = (i == 15) ? 0.f : d;
        }
        #pragma unroll
        for (int co = 0; co < 8; ++co) {
            const float* w9 = wp + co * 27 + ci * 9;
            float w0 = w9[0], w1 = w9[1], w2 = w9[2];
            float w3 = w9[3], w4 = w9[4], w5 = w9[5];
            float w6 = w9[6], w7 = w9[7], w8 = w9[8];
            #pragma unroll
            for (int k = 0; k < 4; ++k) {
                float a = acc[co][k];
                a += up[k]  * w0 + up[k + 1]  * w1 + up[k + 2]  * w2;
                a += own[k] * w3 + own[k + 1] * w4 + own[k + 2] * w5;
                a += dn[k]  * w6 + dn[k + 1]  * w7 + dn[k + 2]  * w8;
                acc[co][k] = a;
            }
        }
    }

    // ---- relu + per-channel sums (butterfly) ----
    float sum8[8];
    #pragma unroll
    for (int co = 0; co < 8; ++co) {
        float v = fmaxf(acc[co][0], 0.f) + fmaxf(acc[co][1], 0.f)
                + fmaxf(acc[co][2], 0.f) + fmaxf(acc[co][3], 0.f);
        #pragma unroll
        for (int off = 1; off < 64; off <<= 1) v += __shfl_xor(v, off, 64);
        sum8[co] = v;
    }

    // lane e writes element e (static-index cndmask chains; no reg-array idx)
    float outv = sum8[0];
    #pragma unroll
    for (int co = 1; co < 8; ++co) outv = (lane == co) ? sum8[co] : outv;
    float pv = prob[0];
    #pragma unroll
    for (int ee = 1; ee < 8; ++ee) pv = (lane == ee) ? prob[ee] : pv;
    if (lane < 8) {
        snc[(size_t)n * 8 + lane] = outv;
        probs[(size_t)n * 8 + lane] = pv;
    }
    if (lane == 0) eidx[n] = am;
}

// ---------------------------------------------------------------------------
// Kernel 2: ordered per-expert rank via packed 16-bit-field u64 wave scan,
// capacity mask, gates, prob-sum reduction, aux loss. One block of 256.
// ---------------------------------------------------------------------------
__global__ __launch_bounds__(256) void k_route(const int* __restrict__ eidx,
        const float* __restrict__ probs, float* __restrict__ gates,
        float* __restrict__ out_aux)
{
    int t = threadIdx.x;
    int wave = t >> 6, lane = t & 63;

    // per-thread counts packed: lo = experts 0..3, hi = 4..7 (16b fields)
    unsigned long long lo = 0ull, hi = 0ull;
    int myE[16];
    #pragma unroll
    for (int k = 0; k < 16; ++k) {
        int e = eidx[t * 16 + k];
        myE[k] = e;
        int sh = 16 * (e & 3);
        if (e < 4) lo += 1ull << sh; else hi += 1ull << sh;
    }

    float lp[8] = {0.f, 0.f, 0.f, 0.f, 0.f, 0.f, 0.f, 0.f};
    #pragma unroll
    for (int k = 0; k < 16; ++k) {
        const float4* p4 = (const float4*)(probs + (size_t)(t * 16 + k) * 8);
        float4 a = p4[0], c = p4[1];
        lp[0] += a.x; lp[1] += a.y; lp[2] += a.z; lp[3] += a.w;
        lp[4] += c.x; lp[5] += c.y; lp[6] += c.z; lp[7] += c.w;
    }

    // inclusive wave scan of packed counts
    unsigned long long slo = lo, shi = hi;
    #pragma unroll
    for (int off = 1; off < 64; off <<= 1) {
        unsigned long long a = __shfl_up(slo, off, 64);
        unsigned long long c = __shfl_up(shi, off, 64);
        if (lane >= off) { slo += a; shi += c; }
    }

    __shared__ unsigned long long wlo[4], whi[4];
    __shared__ float pred[4][8];
    if (lane == 63) { wlo[wave] = slo; whi[wave] = shi; }

    #pragma unroll
    for (int ee = 0; ee < 8; ++ee) {
        float v = lp[ee];
        #pragma unroll
        for (int off = 1; off < 64; off <<= 1) v += __shfl_xor(v, off, 64);
        lp[ee] = v;
    }
    if (lane == 0) {
        pred[wave][0] = lp[0]; pred[wave][1] = lp[1];
        pred[wave][2] = lp[2]; pred[wave][3] = lp[3];
        pred[wave][4] = lp[4]; pred[wave][5] = lp[5];
        pred[wave][6] = lp[6]; pred[wave][7] = lp[7];
    }
    __syncthreads();

    unsigned long long plo = 0ull, phi = 0ull;
    #pragma unroll
    for (int w2 = 0; w2 < 4; ++w2)
        if (w2 < wave) { plo += wlo[w2]; phi += whi[w2]; }
    unsigned long long elo = plo + (slo - lo);   // exclusive prefix (packed)
    unsigned long long ehi = phi + (shi - hi);

    #pragma unroll
    for (int k = 0; k < 16; ++k) {
        int nn = t * 16 + k;
        int e = myE[k];
        int sh = 16 * (e & 3);
        unsigned long long cur = (e < 4) ? elo : ehi;
        int r = (int)((cur >> sh) & 0xFFFFull);
        gates[nn] = (r < CCAP) ? probs[(size_t)nn * 8 + e] : 0.0f;
        unsigned long long inc = 1ull << sh;
        if (e < 4) elo += inc; else ehi += inc;
    }

    if (t == 0) {
        unsigned long long tl = wlo[0] + wlo[1] + wlo[2] + wlo[3];
        unsigned long long th = whi[0] + whi[1] + whi[2] + whi[3];
        float aux = 0.f;
        #pragma unroll
        for (int ee = 0; ee < 8; ++ee) {
            int tot = (ee < 4) ? (int)((tl >> (16 * ee)) & 0xFFFFull)
                               : (int)((th >> (16 * (ee - 4))) & 0xFFFFull);
            float fe = (float)min(tot, CCAP) * (1.0f / 4096.0f);
            float pe = (pred[0][ee] + pred[1][ee] + pred[2][ee] + pred[3][ee])
                       * (1.0f / 4096.0f);
            aux += fe * pe;
        }
        out_aux[0] = 8.0f * aux;
    }
}

// ---------------------------------------------------------------------------
// Kernel 3: feat[b][512] from gate-scaled snc (2x2 patch pool / 1024), then
// logits_cls[b][k] = feat @ lin_w + lin_b. Grid (16,8), block 256:
// 2 threads per column split the f-sum (halves the serial load chain).
// ---------------------------------------------------------------------------
__global__ __launch_bounds__(256) void k_cls(const float* __restrict__ snc,
        const float* __restrict__ gates, const float* __restrict__ lw,
        const float* __restrict__ lb, float* __restrict__ out)
{
    int b = blockIdx.x;
    int chunk = blockIdx.y;
    int tid = threadIdx.x;
    __shared__ float feat[512];
    __shared__ float part[128][2];

    for (int f = tid; f < 512; f += 256) {
        int co = f >> 6, rem = f & 63, py = rem >> 3, pxx = rem & 7;
        float sum = 0.f;
        #pragma unroll
        for (int dy = 0; dy < 2; ++dy)
            #pragma unroll
            for (int dx = 0; dx < 2; ++dx) {
                int nn = b * 256 + (2 * py + dy) * 16 + (2 * pxx + dx);
                sum += gates[nn] * snc[(size_t)nn * 8 + co];
            }
        feat[f] = sum * (1.0f / 1024.0f);
    }
    __syncthreads();

    int col2 = tid >> 1, half = tid & 1;
    int k = chunk * 125 + col2;
    float acc = 0.f;
    if (col2 < 125) {
        const float* lwp = lw + (size_t)(half * 256) * 1000 + k;
        const float* fp = feat + half * 256;
        #pragma unroll 8
        for (int f2 = 0; f2 < 256; ++f2) acc += fp[f2] * lwp[(size_t)f2 * 1000];
    }
    part[col2][half] = acc;
    __syncthreads();
    if (half == 0 && col2 < 125)
        out[b * 1000 + k] = part[col2][0] + part[col2][1] + lb[k];
}

extern "C" void kernel_launch(void* const* d_in, const int* in_sizes, int n_in,
                              void* d_out, int out_size, void* d_ws, size_t ws_size,
                              hipStream_t stream) {
    const float* X  = (const float*)d_in[0];
    const float* ew = (const float*)d_in[1];
    const float* eb = (const float*)d_in[2];
    const float* gw = (const float*)d_in[3];
    const float* gb = (const float*)d_in[4];
    const float* lw = (const float*)d_in[5];
    const float* lb = (const float*)d_in[6];
    float* out = (float*)d_out;

    char* ws = (char*)d_ws;
    int*   eidx  = (int*)  (ws + 0);             // 4096 ints   (16 KB)
    float* probs = (float*)(ws + 16384);         // 4096*8 f    (128 KB)
    float* gates = (float*)(ws + 147456);        // 4096 f      (16 KB)
    float* snc   = (float*)(ws + 163840);        // 4096*8 f    (128 KB)

    k_fused<<<1024, 256, 0, stream>>>(X, gw, gb, ew, eb, eidx, probs, snc);
    k_route<<<1, 256, 0, stream>>>(eidx, probs, gates, out + 16000);
    k_cls<<<dim3(16, 8), 256, 0, stream>>>(snc, gates, lw, lb, out);
}

// Round 6
// 102.904 us; speedup vs baseline: 6.2540x; 1.1147x over previous
//
#include <hip/hip_runtime.h>
#include <math.h>

#define CCAP 640
#define TWO_PI 6.28318530717958647692f

// ---------------------------------------------------------------------------
// Kernel 1 (fused gate+conv, register-only): ONE WAVE PER PATCH.
// Lane layout: i = lane>>2 (row 0..15), q = lane&3 (cols 4q..4q+3).
// - 3x float4 global load (only X read in the whole net)
// - gating sums via butterfly shuffles; ALL lanes compute identical
//   logits/softmax/argmax (deterministic) -> readfirstlane(e) -> scalar
//   weight loads
// - 3x3 SAME conv (patch-local zero pad) with halo via __shfl (no LDS),
//   ReLU, per-channel sums via butterfly -> snc[n][8] (unscaled)
// Outputs: eidx[n], ptop[n] (= top prob), snc[n][8],
//          pspart[block][8] (per-block partial prob sums for aux loss).
// ---------------------------------------------------------------------------
__global__ __launch_bounds__(256) void k_fused(const float* __restrict__ X,
        const float* __restrict__ gw, const float* __restrict__ gb,
        const float* __restrict__ ew, const float* __restrict__ eb,
        int* __restrict__ eidx, float* __restrict__ ptop,
        float* __restrict__ pspart, float* __restrict__ snc)
{
    int tid = threadIdx.x;
    int wave = tid >> 6, lane = tid & 63;
    int n = blockIdx.x * 4 + wave;
    int b = n >> 8, p = n & 255, pr = p >> 4, pc = p & 15;
    int i = lane >> 2, q = lane & 3;

    __shared__ float pb[4][8];

    // ---- load: per-channel float4 strip (cols 4q..4q+3 of row i) ----
    float4 px[3];
    #pragma unroll
    for (int c = 0; c < 3; ++c)
        px[c] = *(const float4*)(X +
            ((size_t)(b * 3 + c) * 256 + pr * 16 + i) * 256 + pc * 16 + q * 4);

    // ---- channel sums (full-wave butterfly -> every lane has total) ----
    float S0, S1, S2;
    {
        float s0 = (px[0].x + px[0].y) + (px[0].z + px[0].w);
        float s1 = (px[1].x + px[1].y) + (px[1].z + px[1].w);
        float s2 = (px[2].x + px[2].y) + (px[2].z + px[2].w);
        #pragma unroll
        for (int off = 1; off < 64; off <<= 1) {
            s0 += __shfl_xor(s0, off, 64);
            s1 += __shfl_xor(s1, off, 64);
            s2 += __shfl_xor(s2, off, 64);
        }
        S0 = s0; S1 = s1; S2 = s2;
    }

    // ---- separable trig sums: lane handles column/row m = lane&15 ----
    int m = lane & 15;
    float tx = (float)(pc * 16 + m) * (1.0f / 256.0f);
    float ty = (float)(pr * 16 + m) * (1.0f / 256.0f);
    float t0 = __sinf(TWO_PI * tx),       t1 = __cosf(TWO_PI * tx);
    float t2 = __sinf(2.f * TWO_PI * tx), t3 = __cosf(2.f * TWO_PI * tx);
    float t4 = __sinf(TWO_PI * ty),       t5 = __cosf(TWO_PI * ty);
    float t6 = __sinf(2.f * TWO_PI * ty), t7 = __cosf(2.f * TWO_PI * ty);
    #pragma unroll
    for (int off = 1; off < 16; off <<= 1) {
        t0 += __shfl_xor(t0, off, 64);  t1 += __shfl_xor(t1, off, 64);
        t2 += __shfl_xor(t2, off, 64);  t3 += __shfl_xor(t3, off, 64);
        t4 += __shfl_xor(t4, off, 64);  t5 += __shfl_xor(t5, off, 64);
        t6 += __shfl_xor(t6, off, 64);  t7 += __shfl_xor(t7, off, 64);
    }

    // ---- logits -> softmax -> argmax (replicated on all 64 lanes) ----
    float pcx = ((float)pc + 0.5f) * (1.0f / 16.0f);
    float pcy = ((float)pr + 0.5f) * (1.0f / 16.0f);
    float S[23];
    S[0] = S0; S[1] = S1; S[2] = S2;
    S[3] = 16.f * ((float)pc + 0.46875f);
    S[4] = 16.f * ((float)pr + 0.46875f);
    S[5] = 256.f * pcx;  S[6] = 256.f * pcy;
    S[7]  = 16.f * t0;  S[8]  = 16.f * t1;
    S[9]  = 16.f * t4;  S[10] = 16.f * t5;
    S[11] = 256.f * __sinf(TWO_PI * pcx);  S[12] = 256.f * __cosf(TWO_PI * pcx);
    S[13] = 256.f * __sinf(TWO_PI * pcy);  S[14] = 256.f * __cosf(TWO_PI * pcy);
    S[15] = 16.f * t2;  S[16] = 16.f * t3;
    S[17] = 16.f * t6;  S[18] = 16.f * t7;
    S[19] = 256.f * __sinf(2.f * TWO_PI * pcx);  S[20] = 256.f * __cosf(2.f * TWO_PI * pcx);
    S[21] = 256.f * __sinf(2.f * TWO_PI * pcy);  S[22] = 256.f * __cosf(2.f * TWO_PI * pcy);

    float lg[8];
    float mx = -1e30f;
    #pragma unroll
    for (int ee = 0; ee < 8; ++ee) {
        float a = 0.f;
        #pragma unroll
        for (int c = 0; c < 23; ++c) a += S[c] * gw[ee * 23 + c];
        lg[ee] = a * (1.0f / 256.0f) + gb[ee];
        mx = fmaxf(mx, lg[ee]);
    }
    float den = 0.f;
    float prob[8];
    #pragma unroll
    for (int ee = 0; ee < 8; ++ee) { prob[ee] = __expf(lg[ee] - mx); den += prob[ee]; }
    float inv = 1.0f / den;
    #pragma unroll
    for (int ee = 0; ee < 8; ++ee) prob[ee] *= inv;
    int am = 0; float best = lg[0];
    #pragma unroll
    for (int ee = 1; ee < 8; ++ee) if (lg[ee] > best) { best = lg[ee]; am = ee; }

    int e = __builtin_amdgcn_readfirstlane(am);
    const float* wp = ew + (size_t)e * 216;

    // ---- conv 3x3 SAME, halo via shuffles, weights scalar ----
    float acc[8][4];
    #pragma unroll
    for (int co = 0; co < 8; ++co) {
        float bv = eb[e * 8 + co];
        #pragma unroll
        for (int k = 0; k < 4; ++k) acc[co][k] = bv;
    }

    #pragma unroll
    for (int ci = 0; ci < 3; ++ci) {
        float4 v = px[ci];
        float own[6];
        own[1] = v.x; own[2] = v.y; own[3] = v.z; own[4] = v.w;
        float L = __shfl(v.w, lane - 1, 64);
        float R = __shfl(v.x, lane + 1, 64);
        own[0] = (q == 0) ? 0.f : L;
        own[5] = (q == 3) ? 0.f : R;
        float up[6], dn[6];
        #pragma unroll
        for (int c6 = 0; c6 < 6; ++c6) {
            float u = __shfl(own[c6], lane - 4, 64);
            float d = __shfl(own[c6], lane + 4, 64);
            up[c6] = (i == 0)  ? 0.f : u;
            dn[c6] = (i == 15) ? 0.f : d;
        }
        #pragma unroll
        for (int co = 0; co < 8; ++co) {
            const float* w9 = wp + co * 27 + ci * 9;
            float w0 = w9[0], w1 = w9[1], w2 = w9[2];
            float w3 = w9[3], w4 = w9[4], w5 = w9[5];
            float w6 = w9[6], w7 = w9[7], w8 = w9[8];
            #pragma unroll
            for (int k = 0; k < 4; ++k) {
                float a = acc[co][k];
                a += up[k]  * w0 + up[k + 1]  * w1 + up[k + 2]  * w2;
                a += own[k] * w3 + own[k + 1] * w4 + own[k + 2] * w5;
                a += dn[k]  * w6 + dn[k + 1]  * w7 + dn[k + 2]  * w8;
                acc[co][k] = a;
            }
        }
    }

    // ---- relu + per-channel sums (butterfly) ----
    float sum8[8];
    #pragma unroll
    for (int co = 0; co < 8; ++co) {
        float v = fmaxf(acc[co][0], 0.f) + fmaxf(acc[co][1], 0.f)
                + fmaxf(acc[co][2], 0.f) + fmaxf(acc[co][3], 0.f);
        #pragma unroll
        for (int off = 1; off < 64; off <<= 1) v += __shfl_xor(v, off, 64);
        sum8[co] = v;
    }

    // lane co holds snc element co; lane ee holds prob[ee] (cndmask chains)
    float outv = sum8[0];
    #pragma unroll
    for (int co = 1; co < 8; ++co) outv = (lane == co) ? sum8[co] : outv;
    float pv = prob[0];
    #pragma unroll
    for (int ee = 1; ee < 8; ++ee) pv = (lane == ee) ? prob[ee] : pv;
    // top prob (am is wave-uniform; static cndmask chain, no reg indexing)
    float tp = prob[0];
    #pragma unroll
    for (int ee = 1; ee < 8; ++ee) tp = (am == ee) ? prob[ee] : tp;

    if (lane < 8) {
        snc[(size_t)n * 8 + lane] = outv;
        pb[wave][lane] = pv;
    }
    if (lane == 0) { eidx[n] = am; ptop[n] = tp; }
    __syncthreads();
    if (tid < 8)
        pspart[(size_t)blockIdx.x * 8 + tid] =
            pb[0][tid] + pb[1][tid] + pb[2][tid] + pb[3][tid];
}

// ---------------------------------------------------------------------------
// Kernel 2 (route + pool + classifier): grid (16 b, 16 chunks), 256 threads.
// Every block REDUNDANTLY recomputes the global route scan (eidx is 16 KB,
// L2-resident) -> gates in LDS; then feat[512] for its batch; then a 64-col
// chunk of logits_cls with 4 f-quarter partials per column.
// Block (0,0) additionally reduces pspart -> aux loss.
// ---------------------------------------------------------------------------
__global__ __launch_bounds__(256) void k_cls(const int* __restrict__ eidx,
        const float* __restrict__ ptop, const float* __restrict__ pspart,
        const float* __restrict__ snc, const float* __restrict__ lw,
        const float* __restrict__ lb, float* __restrict__ out,
        float* __restrict__ out_aux)
{
    int b = blockIdx.x;
    int chunk = blockIdx.y;
    int t = threadIdx.x;
    int wave = t >> 6, lane = t & 63;

    __shared__ float gl[4096];
    __shared__ float feat[512];
    __shared__ unsigned long long wlo[4], whi[4];
    __shared__ float part[64][4];
    __shared__ float pred[4][8];

    // ---- global route scan (packed 16-bit fields: lo=e0..3, hi=e4..7) ----
    unsigned long long lo = 0ull, hi = 0ull;
    int myE[16];
    #pragma unroll
    for (int k4 = 0; k4 < 4; ++k4) {
        int4 v = ((const int4*)eidx)[t * 4 + k4];
        myE[k4 * 4 + 0] = v.x; myE[k4 * 4 + 1] = v.y;
        myE[k4 * 4 + 2] = v.z; myE[k4 * 4 + 3] = v.w;
    }
    #pragma unroll
    for (int k = 0; k < 16; ++k) {
        int e = myE[k];
        int sh = 16 * (e & 3);
        if (e < 4) lo += 1ull << sh; else hi += 1ull << sh;
    }

    unsigned long long slo = lo, shi = hi;
    #pragma unroll
    for (int off = 1; off < 64; off <<= 1) {
        unsigned long long a = __shfl_up(slo, off, 64);
        unsigned long long c = __shfl_up(shi, off, 64);
        if (lane >= off) { slo += a; shi += c; }
    }
    if (lane == 63) { wlo[wave] = slo; whi[wave] = shi; }
    __syncthreads();

    unsigned long long plo = 0ull, phi = 0ull;
    #pragma unroll
    for (int w2 = 0; w2 < 4; ++w2)
        if (w2 < wave) { plo += wlo[w2]; phi += whi[w2]; }
    unsigned long long elo = plo + (slo - lo);   // exclusive prefix (packed)
    unsigned long long ehi = phi + (shi - hi);

    #pragma unroll
    for (int k = 0; k < 16; ++k) {
        int nn = t * 16 + k;
        int e = myE[k];
        int sh = 16 * (e & 3);
        unsigned long long cur = (e < 4) ? elo : ehi;
        int r = (int)((cur >> sh) & 0xFFFFull);
        gl[nn] = (r < CCAP) ? ptop[nn] : 0.0f;
        unsigned long long inc = 1ull << sh;
        if (e < 4) elo += inc; else ehi += inc;
    }
    __syncthreads();

    // ---- feat[512] for batch b (2x2 patch pool of gate-scaled snc) ----
    for (int f = t; f < 512; f += 256) {
        int co = f >> 6, rem = f & 63, py = rem >> 3, pxx = rem & 7;
        float sum = 0.f;
        #pragma unroll
        for (int dy = 0; dy < 2; ++dy)
            #pragma unroll
            for (int dx = 0; dx < 2; ++dx) {
                int nn = b * 256 + (2 * py + dy) * 16 + (2 * pxx + dx);
                sum += gl[nn] * snc[(size_t)nn * 8 + co];
            }
        feat[f] = sum * (1.0f / 1024.0f);
    }
    __syncthreads();

    // ---- 64-column chunk of the classifier, 4 f-quarters per column ----
    int c = t & 63, quarter = t >> 6;       // quarter is wave-uniform
    int kk = chunk * 64 + c;
    int kcl = (kk > 999) ? 999 : kk;        // clamp to stay in-bounds
    float acc = 0.f;
    const float* lp = lw + (size_t)(quarter * 128) * 1000 + kcl;
    const float* fp = feat + quarter * 128;
    #pragma unroll 8
    for (int f2 = 0; f2 < 128; ++f2) acc += fp[f2] * lp[(size_t)f2 * 1000];
    part[c][quarter] = acc;
    __syncthreads();
    if (t < 64) {
        int ko = chunk * 64 + t;
        if (ko < 1000)
            out[b * 1000 + ko] =
                part[t][0] + part[t][1] + part[t][2] + part[t][3] + lb[ko];
    }

    // ---- aux loss (block (0,0) only; block-uniform branch) ----
    if (b == 0 && chunk == 0) {
        float lp8[8] = {0.f, 0.f, 0.f, 0.f, 0.f, 0.f, 0.f, 0.f};
        for (int r = t; r < 1024; r += 256) {
            const float4* p4 = (const float4*)(pspart + (size_t)r * 8);
            float4 a = p4[0], d = p4[1];
            lp8[0] += a.x; lp8[1] += a.y; lp8[2] += a.z; lp8[3] += a.w;
            lp8[4] += d.x; lp8[5] += d.y; lp8[6] += d.z; lp8[7] += d.w;
        }
        #pragma unroll
        for (int ee = 0; ee < 8; ++ee) {
            float v = lp8[ee];
            #pragma unroll
            for (int off = 1; off < 64; off <<= 1) v += __shfl_xor(v, off, 64);
            lp8[ee] = v;
        }
        if (lane == 0) {
            #pragma unroll
            for (int ee = 0; ee < 8; ++ee) pred[wave][ee] = lp8[ee];
        }
        __syncthreads();
        if (t == 0) {
            unsigned long long tl = wlo[0] + wlo[1] + wlo[2] + wlo[3];
            unsigned long long th = whi[0] + whi[1] + whi[2] + whi[3];
            float aux = 0.f;
            #pragma unroll
            for (int ee = 0; ee < 8; ++ee) {
                int tot = (ee < 4) ? (int)((tl >> (16 * ee)) & 0xFFFFull)
                                   : (int)((th >> (16 * (ee - 4))) & 0xFFFFull);
                float fe = (float)min(tot, CCAP) * (1.0f / 4096.0f);
                float pe = (pred[0][ee] + pred[1][ee] + pred[2][ee] + pred[3][ee])
                           * (1.0f / 4096.0f);
                aux += fe * pe;
            }
            out_aux[0] = 8.0f * aux;
        }
    }
}

extern "C" void kernel_launch(void* const* d_in, const int* in_sizes, int n_in,
                              void* d_out, int out_size, void* d_ws, size_t ws_size,
                              hipStream_t stream) {
    const float* X  = (const float*)d_in[0];
    const float* ew = (const float*)d_in[1];
    const float* eb = (const float*)d_in[2];
    const float* gw = (const float*)d_in[3];
    const float* gb = (const float*)d_in[4];
    const float* lw = (const float*)d_in[5];
    const float* lb = (const float*)d_in[6];
    float* out = (float*)d_out;

    char* ws = (char*)d_ws;
    int*   eidx   = (int*)  (ws + 0);        // 4096 ints      (16 KB)
    float* ptop   = (float*)(ws + 16384);    // 4096 floats    (16 KB)
    float* pspart = (float*)(ws + 32768);    // 1024*8 floats  (32 KB)
    float* snc    = (float*)(ws + 65536);    // 4096*8 floats  (128 KB)

    k_fused<<<1024, 256, 0, stream>>>(X, gw, gb, ew, eb, eidx, ptop, pspart, snc);
    k_cls<<<dim3(16, 16), 256, 0, stream>>>(eidx, ptop, pspart, snc, lw, lb,
                                            out, out + 16000);
}

// Round 8
// 102.528 us; speedup vs baseline: 6.2769x; 1.0037x over previous
//
#include <hip/hip_runtime.h>
#include <hip/hip_cooperative_groups.h>
#include <math.h>

namespace cg = cooperative_groups;

#define CCAP 640
#define TWO_PI 6.28318530717958647692f

// ===========================================================================
// Shared device routine: fused gate+conv for ONE patch, executed by one wave.
// Returns via out-params: snc element (lane co), prob[lane] (lane ee),
// top-prob, argmax. Identical math to the verified round-6 k_fused.
// ===========================================================================
__device__ __forceinline__ void patch_gate_conv(
        const float* __restrict__ X,  const float* __restrict__ gw,
        const float* __restrict__ gb, const float* __restrict__ ew,
        const float* __restrict__ eb, int n, int lane,
        float& outv, float& pv, float& tp, int& am_out)
{
    int b = n >> 8, p = n & 255, pr = p >> 4, pc = p & 15;
    int i = lane >> 2, q = lane & 3;

    float4 px[3];
    #pragma unroll
    for (int c = 0; c < 3; ++c)
        px[c] = *(const float4*)(X +
            ((size_t)(b * 3 + c) * 256 + pr * 16 + i) * 256 + pc * 16 + q * 4);

    float S0, S1, S2;
    {
        float s0 = (px[0].x + px[0].y) + (px[0].z + px[0].w);
        float s1 = (px[1].x + px[1].y) + (px[1].z + px[1].w);
        float s2 = (px[2].x + px[2].y) + (px[2].z + px[2].w);
        #pragma unroll
        for (int off = 1; off < 64; off <<= 1) {
            s0 += __shfl_xor(s0, off, 64);
            s1 += __shfl_xor(s1, off, 64);
            s2 += __shfl_xor(s2, off, 64);
        }
        S0 = s0; S1 = s1; S2 = s2;
    }

    int m = lane & 15;
    float tx = (float)(pc * 16 + m) * (1.0f / 256.0f);
    float ty = (float)(pr * 16 + m) * (1.0f / 256.0f);
    float t0 = __sinf(TWO_PI * tx),       t1 = __cosf(TWO_PI * tx);
    float t2 = __sinf(2.f * TWO_PI * tx), t3 = __cosf(2.f * TWO_PI * tx);
    float t4 = __sinf(TWO_PI * ty),       t5 = __cosf(TWO_PI * ty);
    float t6 = __sinf(2.f * TWO_PI * ty), t7 = __cosf(2.f * TWO_PI * ty);
    #pragma unroll
    for (int off = 1; off < 16; off <<= 1) {
        t0 += __shfl_xor(t0, off, 64);  t1 += __shfl_xor(t1, off, 64);
        t2 += __shfl_xor(t2, off, 64);  t3 += __shfl_xor(t3, off, 64);
        t4 += __shfl_xor(t4, off, 64);  t5 += __shfl_xor(t5, off, 64);
        t6 += __shfl_xor(t6, off, 64);  t7 += __shfl_xor(t7, off, 64);
    }

    float pcx = ((float)pc + 0.5f) * (1.0f / 16.0f);
    float pcy = ((float)pr + 0.5f) * (1.0f / 16.0f);
    float S[23];
    S[0] = S0; S[1] = S1; S[2] = S2;
    S[3] = 16.f * ((float)pc + 0.46875f);
    S[4] = 16.f * ((float)pr + 0.46875f);
    S[5] = 256.f * pcx;  S[6] = 256.f * pcy;
    S[7]  = 16.f * t0;  S[8]  = 16.f * t1;
    S[9]  = 16.f * t4;  S[10] = 16.f * t5;
    S[11] = 256.f * __sinf(TWO_PI * pcx);  S[12] = 256.f * __cosf(TWO_PI * pcx);
    S[13] = 256.f * __sinf(TWO_PI * pcy);  S[14] = 256.f * __cosf(TWO_PI * pcy);
    S[15] = 16.f * t2;  S[16] = 16.f * t3;
    S[17] = 16.f * t6;  S[18] = 16.f * t7;
    S[19] = 256.f * __sinf(2.f * TWO_PI * pcx);  S[20] = 256.f * __cosf(2.f * TWO_PI * pcx);
    S[21] = 256.f * __sinf(2.f * TWO_PI * pcy);  S[22] = 256.f * __cosf(2.f * TWO_PI * pcy);

    float lg[8];
    float mx = -1e30f;
    #pragma unroll
    for (int ee = 0; ee < 8; ++ee) {
        float a = 0.f;
        #pragma unroll
        for (int c = 0; c < 23; ++c) a += S[c] * gw[ee * 23 + c];
        lg[ee] = a * (1.0f / 256.0f) + gb[ee];
        mx = fmaxf(mx, lg[ee]);
    }
    float den = 0.f;
    float prob[8];
    #pragma unroll
    for (int ee = 0; ee < 8; ++ee) { prob[ee] = __expf(lg[ee] - mx); den += prob[ee]; }
    float inv = 1.0f / den;
    #pragma unroll
    for (int ee = 0; ee < 8; ++ee) prob[ee] *= inv;
    int am = 0; float best = lg[0];
    #pragma unroll
    for (int ee = 1; ee < 8; ++ee) if (lg[ee] > best) { best = lg[ee]; am = ee; }

    int e = __builtin_amdgcn_readfirstlane(am);
    const float* wp = ew + (size_t)e * 216;

    float acc[8][4];
    #pragma unroll
    for (int co = 0; co < 8; ++co) {
        float bv = eb[e * 8 + co];
        #pragma unroll
        for (int k = 0; k < 4; ++k) acc[co][k] = bv;
    }

    #pragma unroll
    for (int ci = 0; ci < 3; ++ci) {
        float4 v = px[ci];
        float own[6];
        own[1] = v.x; own[2] = v.y; own[3] = v.z; own[4] = v.w;
        float L = __shfl(v.w, lane - 1, 64);
        float R = __shfl(v.x, lane + 1, 64);
        own[0] = (q == 0) ? 0.f : L;
        own[5] = (q == 3) ? 0.f : R;
        float up[6], dn[6];
        #pragma unroll
        for (int c6 = 0; c6 < 6; ++c6) {
            float u = __shfl(own[c6], lane - 4, 64);
            float d = __shfl(own[c6], lane + 4, 64);
            up[c6] = (i == 0)  ? 0.f : u;
            dn[c6] = (i == 15) ? 0.f : d;
        }
        #pragma unroll
        for (int co = 0; co < 8; ++co) {
            const float* w9 = wp + co * 27 + ci * 9;
            float w0 = w9[0], w1 = w9[1], w2 = w9[2];
            float w3 = w9[3], w4 = w9[4], w5 = w9[5];
            float w6 = w9[6], w7 = w9[7], w8 = w9[8];
            #pragma unroll
            for (int k = 0; k < 4; ++k) {
                float a = acc[co][k];
                a += up[k]  * w0 + up[k + 1]  * w1 + up[k + 2]  * w2;
                a += own[k] * w3 + own[k + 1] * w4 + own[k + 2] * w5;
                a += dn[k]  * w6 + dn[k + 1]  * w7 + dn[k + 2]  * w8;
                acc[co][k] = a;
            }
        }
    }

    float sum8[8];
    #pragma unroll
    for (int co = 0; co < 8; ++co) {
        float v = fmaxf(acc[co][0], 0.f) + fmaxf(acc[co][1], 0.f)
                + fmaxf(acc[co][2], 0.f) + fmaxf(acc[co][3], 0.f);
        #pragma unroll
        for (int off = 1; off < 64; off <<= 1) v += __shfl_xor(v, off, 64);
        sum8[co] = v;
    }

    float ov = sum8[0];
    #pragma unroll
    for (int co = 1; co < 8; ++co) ov = (lane == co) ? sum8[co] : ov;
    float pvv = prob[0];
    #pragma unroll
    for (int ee = 1; ee < 8; ++ee) pvv = (lane == ee) ? prob[ee] : pvv;
    float tpv = prob[0];
    #pragma unroll
    for (int ee = 1; ee < 8; ++ee) tpv = (am == ee) ? prob[ee] : tpv;

    outv = ov; pv = pvv; tp = tpv; am_out = am;
}

// ===========================================================================
// Shared device routine: phase 2 (route scan + pool + classifier + aux).
// Executed by blocks bid = 0..255 (b = bid>>4, chunk = bid&15).
// psrows = number of pspart rows to reduce for aux loss.
// ===========================================================================
__device__ __forceinline__ void route_pool_cls(
        const int* __restrict__ eidx, const float* __restrict__ ptop,
        const float* __restrict__ pspart, const float* __restrict__ snc,
        const float* __restrict__ lw, const float* __restrict__ lb,
        float* __restrict__ out, float* __restrict__ out_aux,
        int bid, int t, int psrows,
        float* gl, float* feat, unsigned long long* wlo,
        unsigned long long* whi, float (*part)[4], float (*pred)[8])
{
    int b = bid >> 4;
    int chunk = bid & 15;
    int wave = t >> 6, lane = t & 63;

    unsigned long long lo = 0ull, hi = 0ull;
    int myE[16];
    #pragma unroll
    for (int k4 = 0; k4 < 4; ++k4) {
        int4 v = ((const int4*)eidx)[t * 4 + k4];
        myE[k4 * 4 + 0] = v.x; myE[k4 * 4 + 1] = v.y;
        myE[k4 * 4 + 2] = v.z; myE[k4 * 4 + 3] = v.w;
    }
    #pragma unroll
    for (int k = 0; k < 16; ++k) {
        int e = myE[k];
        int sh = 16 * (e & 3);
        if (e < 4) lo += 1ull << sh; else hi += 1ull << sh;
    }

    unsigned long long slo = lo, shi = hi;
    #pragma unroll
    for (int off = 1; off < 64; off <<= 1) {
        unsigned long long a = __shfl_up(slo, off, 64);
        unsigned long long c = __shfl_up(shi, off, 64);
        if (lane >= off) { slo += a; shi += c; }
    }
    if (lane == 63) { wlo[wave] = slo; whi[wave] = shi; }
    __syncthreads();

    unsigned long long plo = 0ull, phi = 0ull;
    #pragma unroll
    for (int w2 = 0; w2 < 4; ++w2)
        if (w2 < wave) { plo += wlo[w2]; phi += whi[w2]; }
    unsigned long long elo = plo + (slo - lo);
    unsigned long long ehi = phi + (shi - hi);

    #pragma unroll
    for (int k = 0; k < 16; ++k) {
        int nn = t * 16 + k;
        int e = myE[k];
        int sh = 16 * (e & 3);
        unsigned long long cur = (e < 4) ? elo : ehi;
        int r = (int)((cur >> sh) & 0xFFFFull);
        gl[nn] = (r < CCAP) ? ptop[nn] : 0.0f;
        unsigned long long inc = 1ull << sh;
        if (e < 4) elo += inc; else ehi += inc;
    }
    __syncthreads();

    for (int f = t; f < 512; f += 256) {
        int co = f >> 6, rem = f & 63, py = rem >> 3, pxx = rem & 7;
        float sum = 0.f;
        #pragma unroll
        for (int dy = 0; dy < 2; ++dy)
            #pragma unroll
            for (int dx = 0; dx < 2; ++dx) {
                int nn = b * 256 + (2 * py + dy) * 16 + (2 * pxx + dx);
                sum += gl[nn] * snc[(size_t)nn * 8 + co];
            }
        feat[f] = sum * (1.0f / 1024.0f);
    }
    __syncthreads();

    int c = t & 63, quarter = t >> 6;
    int kk = chunk * 64 + c;
    int kcl = (kk > 999) ? 999 : kk;
    float acc = 0.f;
    const float* lp = lw + (size_t)(quarter * 128) * 1000 + kcl;
    const float* fp = feat + quarter * 128;
    #pragma unroll 8
    for (int f2 = 0; f2 < 128; ++f2) acc += fp[f2] * lp[(size_t)f2 * 1000];
    part[c][quarter] = acc;
    __syncthreads();
    if (t < 64) {
        int ko = chunk * 64 + t;
        if (ko < 1000)
            out[b * 1000 + ko] =
                part[t][0] + part[t][1] + part[t][2] + part[t][3] + lb[ko];
    }

    if (bid == 0) {
        float lp8[8] = {0.f, 0.f, 0.f, 0.f, 0.f, 0.f, 0.f, 0.f};
        for (int r = t; r < psrows; r += 256) {
            const float4* p4 = (const float4*)(pspart + (size_t)r * 8);
            float4 a = p4[0], d = p4[1];
            lp8[0] += a.x; lp8[1] += a.y; lp8[2] += a.z; lp8[3] += a.w;
            lp8[4] += d.x; lp8[5] += d.y; lp8[6] += d.z; lp8[7] += d.w;
        }
        #pragma unroll
        for (int ee = 0; ee < 8; ++ee) {
            float v = lp8[ee];
            #pragma unroll
            for (int off = 1; off < 64; off <<= 1) v += __shfl_xor(v, off, 64);
            lp8[ee] = v;
        }
        if (lane == 0) {
            #pragma unroll
            for (int ee = 0; ee < 8; ++ee) pred[wave][ee] = lp8[ee];
        }
        __syncthreads();
        if (t == 0) {
            unsigned long long tl = wlo[0] + wlo[1] + wlo[2] + wlo[3];
            unsigned long long th = whi[0] + whi[1] + whi[2] + whi[3];
            float aux = 0.f;
            #pragma unroll
            for (int ee = 0; ee < 8; ++ee) {
                int tot = (ee < 4) ? (int)((tl >> (16 * ee)) & 0xFFFFull)
                                   : (int)((th >> (16 * (ee - 4))) & 0xFFFFull);
                float fe = (float)min(tot, CCAP) * (1.0f / 4096.0f);
                float pe = (pred[0][ee] + pred[1][ee] + pred[2][ee] + pred[3][ee])
                           * (1.0f / 4096.0f);
                aux += fe * pe;
            }
            out_aux[0] = 8.0f * aux;
        }
    }
}

// ===========================================================================
// Cooperative single kernel: 512 blocks x 256 threads, 2 blocks/CU needed
// (comfortable margin on every resource axis). Each wave does 2 patches in
// phase 1; blocks 0..255 run phase 2 after the grid sync.
// ===========================================================================
__global__ __launch_bounds__(256, 2) void k_all_coop(
        const float* __restrict__ X,  const float* __restrict__ gw,
        const float* __restrict__ gb, const float* __restrict__ ew,
        const float* __restrict__ eb, const float* __restrict__ lw,
        const float* __restrict__ lb, int* __restrict__ eidx,
        float* __restrict__ ptop, float* __restrict__ pspart,
        float* __restrict__ snc, float* __restrict__ out,
        float* __restrict__ out_aux)
{
    int tid = threadIdx.x;
    int wave = tid >> 6, lane = tid & 63;

    __shared__ float pb[4][8];
    __shared__ float gl[4096];
    __shared__ float feat[512];
    __shared__ unsigned long long wlo[4], whi[4];
    __shared__ float part[64][4];
    __shared__ float pred[4][8];

    // ---- phase 1: 2 patches per wave ----
    {
        float pvacc = 0.f;
        #pragma unroll
        for (int k = 0; k < 2; ++k) {
            int n = blockIdx.x * 8 + wave * 2 + k;
            float outv, pv, tp; int am;
            patch_gate_conv(X, gw, gb, ew, eb, n, lane, outv, pv, tp, am);
            if (lane < 8) snc[(size_t)n * 8 + lane] = outv;
            if (lane == 0) { eidx[n] = am; ptop[n] = tp; }
            pvacc += pv;
        }
        if (lane < 8) pb[wave][lane] = pvacc;
        __syncthreads();
        if (tid < 8)
            pspart[(size_t)blockIdx.x * 8 + tid] =
                pb[0][tid] + pb[1][tid] + pb[2][tid] + pb[3][tid];
    }

    __threadfence();
    cg::this_grid().sync();
    if (blockIdx.x >= 256) return;

    route_pool_cls(eidx, ptop, pspart, snc, lw, lb, out, out_aux,
                   blockIdx.x, tid, 512, gl, feat, wlo, whi, part, pred);
}

// ===========================================================================
// Fallback path: the verified round-6 two-kernel pipeline (byte-identical
// math; k_fused 1024 blocks x 1 patch/wave, k_cls 256 blocks).
// ===========================================================================
__global__ __launch_bounds__(256) void k_fused(const float* __restrict__ X,
        const float* __restrict__ gw, const float* __restrict__ gb,
        const float* __restrict__ ew, const float* __restrict__ eb,
        int* __restrict__ eidx, float* __restrict__ ptop,
        float* __restrict__ pspart, float* __restrict__ snc)
{
    int tid = threadIdx.x;
    int wave = tid >> 6, lane = tid & 63;
    int n = blockIdx.x * 4 + wave;

    __shared__ float pb[4][8];

    float outv, pv, tp; int am;
    patch_gate_conv(X, gw, gb, ew, eb, n, lane, outv, pv, tp, am);

    if (lane < 8) {
        snc[(size_t)n * 8 + lane] = outv;
        pb[wave][lane] = pv;
    }
    if (lane == 0) { eidx[n] = am; ptop[n] = tp; }
    __syncthreads();
    if (tid < 8)
        pspart[(size_t)blockIdx.x * 8 + tid] =
            pb[0][tid] + pb[1][tid] + pb[2][tid] + pb[3][tid];
}

__global__ __launch_bounds__(256) void k_cls(const int* __restrict__ eidx,
        const float* __restrict__ ptop, const float* __restrict__ pspart,
        const float* __restrict__ snc, const float* __restrict__ lw,
        const float* __restrict__ lb, float* __restrict__ out,
        float* __restrict__ out_aux)
{
    __shared__ float gl[4096];
    __shared__ float feat[512];
    __shared__ unsigned long long wlo[4], whi[4];
    __shared__ float part[64][4];
    __shared__ float pred[4][8];

    int bid = blockIdx.x * 16 + blockIdx.y;   // grid (16,16): b*16+chunk
    route_pool_cls(eidx, ptop, pspart, snc, lw, lb, out, out_aux,
                   bid, threadIdx.x, 1024, gl, feat, wlo, whi, part, pred);
}

extern "C" void kernel_launch(void* const* d_in, const int* in_sizes, int n_in,
                              void* d_out, int out_size, void* d_ws, size_t ws_size,
                              hipStream_t stream) {
    const float* X  = (const float*)d_in[0];
    const float* ew = (const float*)d_in[1];
    const float* eb = (const float*)d_in[2];
    const float* gw = (const float*)d_in[3];
    const float* gb = (const float*)d_in[4];
    const float* lw = (const float*)d_in[5];
    const float* lb = (const float*)d_in[6];
    float* out = (float*)d_out;
    float* out_aux = out + 16000;

    char* ws = (char*)d_ws;
    int*   eidx   = (int*)  (ws + 0);        // 4096 ints      (16 KB)
    float* ptop   = (float*)(ws + 16384);    // 4096 floats    (16 KB)
    float* pspart = (float*)(ws + 32768);    // <=1024*8 f     (32 KB)
    float* snc    = (float*)(ws + 65536);    // 4096*8 floats  (128 KB)

    // Deterministic guard: only use the cooperative path if the driver
    // guarantees >=2 resident blocks/CU (512 blocks on 256 CUs).
    int maxB = 0;
    hipError_t qe = hipOccupancyMaxActiveBlocksPerMultiprocessor(
        &maxB, (const void*)k_all_coop, 256, 0);
    bool coop = (qe == hipSuccess && maxB >= 2);

    if (coop) {
        void* args[] = { (void*)&X, (void*)&gw, (void*)&gb, (void*)&ew,
                         (void*)&eb, (void*)&lw, (void*)&lb, (void*)&eidx,
                         (void*)&ptop, (void*)&pspart, (void*)&snc,
                         (void*)&out, (void*)&out_aux };
        hipError_t le = hipLaunchCooperativeKernel((const void*)k_all_coop,
                                                   dim3(512), dim3(256),
                                                   args, 0, stream);
        if (le == hipSuccess) return;
        (void)hipGetLastError();   // clear and fall through to fallback
    }

    k_fused<<<1024, 256, 0, stream>>>(X, gw, gb, ew, eb, eidx, ptop, pspart, snc);
    k_cls<<<dim3(16, 16), 256, 0, stream>>>(eidx, ptop, pspart, snc, lw, lb,
                                            out, out_aux);
}

// Round 9
// 101.919 us; speedup vs baseline: 6.3144x; 1.0060x over previous
//
#include <hip/hip_runtime.h>
#include <math.h>

#define CCAP 640
#define TWO_PI 6.28318530717958647692f

// ===========================================================================
// Fused gate+conv for ONE patch, executed by one wave (verified R6 math;
// gating logits now computed lane-parallel — bit-identical results).
// ===========================================================================
__device__ __forceinline__ void patch_gate_conv(
        const float* __restrict__ X,  const float* __restrict__ gw,
        const float* __restrict__ gb, const float* __restrict__ ew,
        const float* __restrict__ eb, int n, int lane,
        float& outv, float& pv, float& tp, int& am_out)
{
    int b = n >> 8, p = n & 255, pr = p >> 4, pc = p & 15;
    int i = lane >> 2, q = lane & 3;

    float4 px[3];
    #pragma unroll
    for (int c = 0; c < 3; ++c)
        px[c] = *(const float4*)(X +
            ((size_t)(b * 3 + c) * 256 + pr * 16 + i) * 256 + pc * 16 + q * 4);

    float S0, S1, S2;
    {
        float s0 = (px[0].x + px[0].y) + (px[0].z + px[0].w);
        float s1 = (px[1].x + px[1].y) + (px[1].z + px[1].w);
        float s2 = (px[2].x + px[2].y) + (px[2].z + px[2].w);
        #pragma unroll
        for (int off = 1; off < 64; off <<= 1) {
            s0 += __shfl_xor(s0, off, 64);
            s1 += __shfl_xor(s1, off, 64);
            s2 += __shfl_xor(s2, off, 64);
        }
        S0 = s0; S1 = s1; S2 = s2;
    }

    int m = lane & 15;
    float tx = (float)(pc * 16 + m) * (1.0f / 256.0f);
    float ty = (float)(pr * 16 + m) * (1.0f / 256.0f);
    float t0 = __sinf(TWO_PI * tx),       t1 = __cosf(TWO_PI * tx);
    float t2 = __sinf(2.f * TWO_PI * tx), t3 = __cosf(2.f * TWO_PI * tx);
    float t4 = __sinf(TWO_PI * ty),       t5 = __cosf(TWO_PI * ty);
    float t6 = __sinf(2.f * TWO_PI * ty), t7 = __cosf(2.f * TWO_PI * ty);
    #pragma unroll
    for (int off = 1; off < 16; off <<= 1) {
        t0 += __shfl_xor(t0, off, 64);  t1 += __shfl_xor(t1, off, 64);
        t2 += __shfl_xor(t2, off, 64);  t3 += __shfl_xor(t3, off, 64);
        t4 += __shfl_xor(t4, off, 64);  t5 += __shfl_xor(t5, off, 64);
        t6 += __shfl_xor(t6, off, 64);  t7 += __shfl_xor(t7, off, 64);
    }

    float pcx = ((float)pc + 0.5f) * (1.0f / 16.0f);
    float pcy = ((float)pr + 0.5f) * (1.0f / 16.0f);
    float S[23];
    S[0] = S0; S[1] = S1; S[2] = S2;
    S[3] = 16.f * ((float)pc + 0.46875f);
    S[4] = 16.f * ((float)pr + 0.46875f);
    S[5] = 256.f * pcx;  S[6] = 256.f * pcy;
    S[7]  = 16.f * t0;  S[8]  = 16.f * t1;
    S[9]  = 16.f * t4;  S[10] = 16.f * t5;
    S[11] = 256.f * __sinf(TWO_PI * pcx);  S[12] = 256.f * __cosf(TWO_PI * pcx);
    S[13] = 256.f * __sinf(TWO_PI * pcy);  S[14] = 256.f * __cosf(TWO_PI * pcy);
    S[15] = 16.f * t2;  S[16] = 16.f * t3;
    S[17] = 16.f * t6;  S[18] = 16.f * t7;
    S[19] = 256.f * __sinf(2.f * TWO_PI * pcx);  S[20] = 256.f * __cosf(2.f * TWO_PI * pcx);
    S[21] = 256.f * __sinf(2.f * TWO_PI * pcy);  S[22] = 256.f * __cosf(2.f * TWO_PI * pcy);

    // ---- gating logits, LANE-PARALLEL: lane group computes expert lane&7.
    // Same sequential c-order as the replicated version -> bit-identical. ----
    float lgmine;
    {
        int eemy = lane & 7;
        const float* gwp = gw + eemy * 23;
        float a = 0.f;
        #pragma unroll
        for (int c = 0; c < 23; ++c) a += S[c] * gwp[c];
        lgmine = a * (1.0f / 256.0f) + gb[eemy];
    }
    float lg[8];
    #pragma unroll
    for (int ee = 0; ee < 8; ++ee) lg[ee] = __shfl(lgmine, ee, 64);

    float mx = -1e30f;
    #pragma unroll
    for (int ee = 0; ee < 8; ++ee) mx = fmaxf(mx, lg[ee]);
    float den = 0.f;
    float prob[8];
    #pragma unroll
    for (int ee = 0; ee < 8; ++ee) { prob[ee] = __expf(lg[ee] - mx); den += prob[ee]; }
    float inv = 1.0f / den;
    #pragma unroll
    for (int ee = 0; ee < 8; ++ee) prob[ee] *= inv;
    int am = 0; float best = lg[0];
    #pragma unroll
    for (int ee = 1; ee < 8; ++ee) if (lg[ee] > best) { best = lg[ee]; am = ee; }

    int e = __builtin_amdgcn_readfirstlane(am);
    const float* wp = ew + (size_t)e * 216;

    float acc[8][4];
    #pragma unroll
    for (int co = 0; co < 8; ++co) {
        float bv = eb[e * 8 + co];
        #pragma unroll
        for (int k = 0; k < 4; ++k) acc[co][k] = bv;
    }

    #pragma unroll
    for (int ci = 0; ci < 3; ++ci) {
        float4 v = px[ci];
        float own[6];
        own[1] = v.x; own[2] = v.y; own[3] = v.z; own[4] = v.w;
        float L = __shfl(v.w, lane - 1, 64);
        float R = __shfl(v.x, lane + 1, 64);
        own[0] = (q == 0) ? 0.f : L;
        own[5] = (q == 3) ? 0.f : R;
        float up[6], dn[6];
        #pragma unroll
        for (int c6 = 0; c6 < 6; ++c6) {
            float u = __shfl(own[c6], lane - 4, 64);
            float d = __shfl(own[c6], lane + 4, 64);
            up[c6] = (i == 0)  ? 0.f : u;
            dn[c6] = (i == 15) ? 0.f : d;
        }
        #pragma unroll
        for (int co = 0; co < 8; ++co) {
            const float* w9 = wp + co * 27 + ci * 9;
            float w0 = w9[0], w1 = w9[1], w2 = w9[2];
            float w3 = w9[3], w4 = w9[4], w5 = w9[5];
            float w6 = w9[6], w7 = w9[7], w8 = w9[8];
            #pragma unroll
            for (int k = 0; k < 4; ++k) {
                float a = acc[co][k];
                a += up[k]  * w0 + up[k + 1]  * w1 + up[k + 2]  * w2;
                a += own[k] * w3 + own[k + 1] * w4 + own[k + 2] * w5;
                a += dn[k]  * w6 + dn[k + 1]  * w7 + dn[k + 2]  * w8;
                acc[co][k] = a;
            }
        }
    }

    float sum8[8];
    #pragma unroll
    for (int co = 0; co < 8; ++co) {
        float v = fmaxf(acc[co][0], 0.f) + fmaxf(acc[co][1], 0.f)
                + fmaxf(acc[co][2], 0.f) + fmaxf(acc[co][3], 0.f);
        #pragma unroll
        for (int off = 1; off < 64; off <<= 1) v += __shfl_xor(v, off, 64);
        sum8[co] = v;
    }

    float ov = sum8[0];
    #pragma unroll
    for (int co = 1; co < 8; ++co) ov = (lane == co) ? sum8[co] : ov;
    float pvv = prob[0];
    #pragma unroll
    for (int ee = 1; ee < 8; ++ee) pvv = (lane == ee) ? prob[ee] : pvv;
    float tpv = prob[0];
    #pragma unroll
    for (int ee = 1; ee < 8; ++ee) tpv = (am == ee) ? prob[ee] : tpv;

    outv = ov; pv = pvv; tp = tpv; am_out = am;
}

// ===========================================================================
// Phase 2: route scan + pool + classifier + aux (verified R6 math).
// ===========================================================================
__device__ __forceinline__ void route_pool_cls(
        const int* __restrict__ eidx, const float* __restrict__ ptop,
        const float* __restrict__ pspart, const float* __restrict__ snc,
        const float* __restrict__ lw, const float* __restrict__ lb,
        float* __restrict__ out, float* __restrict__ out_aux,
        int bid, int t, int psrows,
        float* gl, float* feat, unsigned long long* wlo,
        unsigned long long* whi, float (*part)[4], float (*pred)[8])
{
    int b = bid >> 4;
    int chunk = bid & 15;
    int wave = t >> 6, lane = t & 63;

    unsigned long long lo = 0ull, hi = 0ull;
    int myE[16];
    #pragma unroll
    for (int k4 = 0; k4 < 4; ++k4) {
        int4 v = ((const int4*)eidx)[t * 4 + k4];
        myE[k4 * 4 + 0] = v.x; myE[k4 * 4 + 1] = v.y;
        myE[k4 * 4 + 2] = v.z; myE[k4 * 4 + 3] = v.w;
    }
    #pragma unroll
    for (int k = 0; k < 16; ++k) {
        int e = myE[k];
        int sh = 16 * (e & 3);
        if (e < 4) lo += 1ull << sh; else hi += 1ull << sh;
    }

    unsigned long long slo = lo, shi = hi;
    #pragma unroll
    for (int off = 1; off < 64; off <<= 1) {
        unsigned long long a = __shfl_up(slo, off, 64);
        unsigned long long c = __shfl_up(shi, off, 64);
        if (lane >= off) { slo += a; shi += c; }
    }
    if (lane == 63) { wlo[wave] = slo; whi[wave] = shi; }
    __syncthreads();

    unsigned long long plo = 0ull, phi = 0ull;
    #pragma unroll
    for (int w2 = 0; w2 < 4; ++w2)
        if (w2 < wave) { plo += wlo[w2]; phi += whi[w2]; }
    unsigned long long elo = plo + (slo - lo);
    unsigned long long ehi = phi + (shi - hi);

    #pragma unroll
    for (int k = 0; k < 16; ++k) {
        int nn = t * 16 + k;
        int e = myE[k];
        int sh = 16 * (e & 3);
        unsigned long long cur = (e < 4) ? elo : ehi;
        int r = (int)((cur >> sh) & 0xFFFFull);
        gl[nn] = (r < CCAP) ? ptop[nn] : 0.0f;
        unsigned long long inc = 1ull << sh;
        if (e < 4) elo += inc; else ehi += inc;
    }
    __syncthreads();

    for (int f = t; f < 512; f += 256) {
        int co = f >> 6, rem = f & 63, py = rem >> 3, pxx = rem & 7;
        float sum = 0.f;
        #pragma unroll
        for (int dy = 0; dy < 2; ++dy)
            #pragma unroll
            for (int dx = 0; dx < 2; ++dx) {
                int nn = b * 256 + (2 * py + dy) * 16 + (2 * pxx + dx);
                sum += gl[nn] * snc[(size_t)nn * 8 + co];
            }
        feat[f] = sum * (1.0f / 1024.0f);
    }
    __syncthreads();

    int c = t & 63, quarter = t >> 6;
    int kk = chunk * 64 + c;
    int kcl = (kk > 999) ? 999 : kk;
    float acc = 0.f;
    const float* lp = lw + (size_t)(quarter * 128) * 1000 + kcl;
    const float* fp = feat + quarter * 128;
    #pragma unroll 8
    for (int f2 = 0; f2 < 128; ++f2) acc += fp[f2] * lp[(size_t)f2 * 1000];
    part[c][quarter] = acc;
    __syncthreads();
    if (t < 64) {
        int ko = chunk * 64 + t;
        if (ko < 1000)
            out[b * 1000 + ko] =
                part[t][0] + part[t][1] + part[t][2] + part[t][3] + lb[ko];
    }

    if (bid == 0) {
        float lp8[8] = {0.f, 0.f, 0.f, 0.f, 0.f, 0.f, 0.f, 0.f};
        for (int r = t; r < psrows; r += 256) {
            const float4* p4 = (const float4*)(pspart + (size_t)r * 8);
            float4 a = p4[0], d = p4[1];
            lp8[0] += a.x; lp8[1] += a.y; lp8[2] += a.z; lp8[3] += a.w;
            lp8[4] += d.x; lp8[5] += d.y; lp8[6] += d.z; lp8[7] += d.w;
        }
        #pragma unroll
        for (int ee = 0; ee < 8; ++ee) {
            float v = lp8[ee];
            #pragma unroll
            for (int off = 1; off < 64; off <<= 1) v += __shfl_xor(v, off, 64);
            lp8[ee] = v;
        }
        if (lane == 0) {
            #pragma unroll
            for (int ee = 0; ee < 8; ++ee) pred[wave][ee] = lp8[ee];
        }
        __syncthreads();
        if (t == 0) {
            unsigned long long tl = wlo[0] + wlo[1] + wlo[2] + wlo[3];
            unsigned long long th = whi[0] + whi[1] + whi[2] + whi[3];
            float aux = 0.f;
            #pragma unroll
            for (int ee = 0; ee < 8; ++ee) {
                int tot = (ee < 4) ? (int)((tl >> (16 * ee)) & 0xFFFFull)
                                   : (int)((th >> (16 * (ee - 4))) & 0xFFFFull);
                float fe = (float)min(tot, CCAP) * (1.0f / 4096.0f);
                float pe = (pred[0][ee] + pred[1][ee] + pred[2][ee] + pred[3][ee])
                           * (1.0f / 4096.0f);
                aux += fe * pe;
            }
            out_aux[0] = 8.0f * aux;
        }
    }
}

__global__ __launch_bounds__(256) void k_fused(const float* __restrict__ X,
        const float* __restrict__ gw, const float* __restrict__ gb,
        const float* __restrict__ ew, const float* __restrict__ eb,
        int* __restrict__ eidx, float* __restrict__ ptop,
        float* __restrict__ pspart, float* __restrict__ snc)
{
    int tid = threadIdx.x;
    int wave = tid >> 6, lane = tid & 63;
    int n = blockIdx.x * 4 + wave;

    __shared__ float pb[4][8];

    float outv, pv, tp; int am;
    patch_gate_conv(X, gw, gb, ew, eb, n, lane, outv, pv, tp, am);

    if (lane < 8) {
        snc[(size_t)n * 8 + lane] = outv;
        pb[wave][lane] = pv;
    }
    if (lane == 0) { eidx[n] = am; ptop[n] = tp; }
    __syncthreads();
    if (tid < 8)
        pspart[(size_t)blockIdx.x * 8 + tid] =
            pb[0][tid] + pb[1][tid] + pb[2][tid] + pb[3][tid];
}

__global__ __launch_bounds__(256) void k_cls(const int* __restrict__ eidx,
        const float* __restrict__ ptop, const float* __restrict__ pspart,
        const float* __restrict__ snc, const float* __restrict__ lw,
        const float* __restrict__ lb, float* __restrict__ out,
        float* __restrict__ out_aux)
{
    __shared__ float gl[4096];
    __shared__ float feat[512];
    __shared__ unsigned long long wlo[4], whi[4];
    __shared__ float part[64][4];
    __shared__ float pred[4][8];

    int bid = blockIdx.x * 16 + blockIdx.y;   // grid (16,16): b*16+chunk
    route_pool_cls(eidx, ptop, pspart, snc, lw, lb, out, out_aux,
                   bid, threadIdx.x, 1024, gl, feat, wlo, whi, part, pred);
}

extern "C" void kernel_launch(void* const* d_in, const int* in_sizes, int n_in,
                              void* d_out, int out_size, void* d_ws, size_t ws_size,
                              hipStream_t stream) {
    const float* X  = (const float*)d_in[0];
    const float* ew = (const float*)d_in[1];
    const float* eb = (const float*)d_in[2];
    const float* gw = (const float*)d_in[3];
    const float* gb = (const float*)d_in[4];
    const float* lw = (const float*)d_in[5];
    const float* lb = (const float*)d_in[6];
    float* out = (float*)d_out;
    float* out_aux = out + 16000;

    char* ws = (char*)d_ws;
    int*   eidx   = (int*)  (ws + 0);        // 4096 ints      (16 KB)
    float* ptop   = (float*)(ws + 16384);    // 4096 floats    (16 KB)
    float* pspart = (float*)(ws + 32768);    // 1024*8 floats  (32 KB)
    float* snc    = (float*)(ws + 65536);    // 4096*8 floats  (128 KB)

    k_fused<<<1024, 256, 0, stream>>>(X, gw, gb, ew, eb, eidx, ptop, pspart, snc);
    k_cls<<<dim3(16, 16), 256, 0, stream>>>(eidx, ptop, pspart, snc, lw, lb,
                                            out, out_aux);
}